// Round 1
// 4498.597 us; speedup vs baseline: 1.2992x; 1.2992x over previous
//
#include <hip/hip_runtime.h>
#include <math.h>

// ============================================================================
// S2CNN regression — round 4.
//  R3 profile: the four ~835us k_gemm rows are the SAME dispatch (block-1
//  conv-a, 17.2 GFLOP) across iterations -> single dominant kernel at 13% of
//  f32 peak, VALUBusy 56%, occupancy 22% (imbalanced per-l K-loops + heavy
//  staging overhead).
//  This round: rank-6 factorization of the conv kernel. wf only sees p,ni
//  through mod-6 residues, so
//     y = sum_{c,mm} wf[c,f,mm,nn(ni)] * sum_{p=l+mm (6)} xh[b,c,mi,p]*d0[p,ni]
//  cuts FLOPs by 6/d + 1/(2F) (7.9x for the dominant conv). Implemented as a
//  fused kernel k_gemm2: xt tile built on the fly into LDS (<=11-step j-loop,
//  broadcast xh / coalesced d0 loads), K=6C uniform across l (load-balanced),
//  coalesced stores. Old k_gemm kept for L==2 where d<6 makes this a loss.
// ============================================================================

#define PI_D 3.14159265358979323846

__host__ __device__ __forceinline__ int offl_(int l) { return l*(2*l-1)*(2*l+1)/3; }
static inline int Sof(int b) { return b*(4*b*b-1)/3; }           // sum_{l<b}(2l+1)^2
static inline unsigned cdiv(long a, long b) { return (unsigned)((a + b - 1) / b); }

__device__ __constant__ float COS6[6] = {1.f, .5f, -.5f, -1.f, -.5f, .5f};
__device__ __constant__ float SIN6[6] = {0.f, 0.8660254037844386f, 0.8660254037844386f,
                                         0.f, -0.8660254037844386f, -0.8660254037844386f};

// ---------------- table generation ----------------
__global__ void k_lf(double* lf) {
  int n = threadIdx.x;
  double s = 0.0;
  for (int j = 2; j <= n; ++j) s += log((double)j);
  lf[n] = s;
}

__global__ void k_qw(int b, float* out) {
  int k = threadIdx.x, K = 2*b;
  if (k >= K) return;
  double beta = PI_D*(2*k+1)/(4.0*b);
  double s = 0.0;
  for (int j = 0; j < b; ++j)
    s += sin(PI_D*(double)(2*k+1)*(double)(2*j+1)/(4.0*b)) / (double)(2*j+1);
  out[k] = (float)((2.0/b)*sin(beta)*s);
}

// d^l_{m,n}(beta), explicit Jacobi sum, fp64.
// Layout: out[K*offl(l) + k*(2l+1)^2 + (m+l)*(2l+1) + (n+l)]
__global__ void k_wigner(int L, int K, double beta0, const double* __restrict__ lf,
                         float* __restrict__ out) {
  int l = blockIdx.y;
  int d = 2*l+1, dd = d*d;
  long total = (long)K*dd;
  long idx = (long)blockIdx.x*blockDim.x + threadIdx.x;
  if (idx >= total) return;
  int k = (int)(idx / dd), r = (int)(idx % dd);
  int mi = r/d, ni = r - mi*d, m = mi-l, n = ni-l;
  double beta = (K == 1) ? beta0 : PI_D*(double)(2*k+1)/(2.0*K);
  double cb = cos(0.5*beta), sb = sin(0.5*beta);
  double lc = log(cb), ls = log(sb);
  double pref = 0.5*(lf[l+m]+lf[l-m]+lf[l+n]+lf[l-n]);
  int smin = (n-m > 0) ? (n-m) : 0;
  int smax = (l+n < l-m) ? (l+n) : (l-m);
  double sum = 0.0;
  for (int s = smin; s <= smax; ++s) {
    double t = pref - lf[l+n-s] - lf[s] - lf[m-n+s] - lf[l-m-s]
             + (double)(2*l+n-m-2*s)*lc + (double)(m-n+2*s)*ls;
    double e = exp(t);
    sum += ((m-n+s) & 1) ? -e : e;
  }
  out[(long)K*offl_(l) + idx] = (float)sum;
}

// ---------------- s2 front: 1-D forward DFT (centered output) ----------------
__global__ void k_dft1(const float* __restrict__ in, float2* __restrict__ out, int K) {
  __shared__ float row[64];
  int tid = threadIdx.x;
  long base = (long)blockIdx.x * K;
  row[tid] = in[base + tid];
  __syncthreads();
  int i = tid;
  float2 acc = make_float2(0.f, 0.f);
  float c0 = 6.28318530717958647692f / K;
  for (int j = 0; j < K; ++j) {
    int r = (j * ((K + K/2 - i) & (K-1))) & (K-1);
    float s, c; sincosf(c0 * (float)r, &s, &c);
    acc.x += row[j]*c; acc.y += row[j]*s;
  }
  out[base + i] = acc;
}

// ---------------- fused transition kernel ----------------
__device__ __forceinline__ void fft_axis(float2* T, int P, float2* S, const float2* TW,
                                         int K, int axis, float fsign,
                                         int tid, int bs) {
  const int half = K >> 1;
  int stages = 0; for (int t = K; t > 1; t >>= 1) ++stages;
  for (int b0 = 0; b0 < K; b0 += half) {
    int cur = 0;                       // 0: data in T, 1: in S
    int l = half, m = 1;
    for (int s = 0; s < stages; ++s) {
      for (int t = tid; t < half*half; t += bs) {
        int line = t / half, b = t - (t/half)*half;
        int j = b / m, k = b - (b/m)*m;
        int i0 = k + j*m, i1 = i0 + l*m;
        int o0 = k + 2*j*m, o1 = o0 + m;
        float2 a, bb;
        if (cur == 0) {
          int t0i = axis ? (i0*P + b0 + line) : ((b0+line)*P + i0);
          int t1i = axis ? (i1*P + b0 + line) : ((b0+line)*P + i1);
          a = T[t0i]; bb = T[t1i];
        } else {
          a = S[line*K + i0]; bb = S[line*K + i1];
        }
        float2 w = TW[j*m]; w.y *= fsign;
        float2 dv = make_float2(a.x - bb.x, a.y - bb.y);
        float2 t1 = make_float2(dv.x*w.x - dv.y*w.y, dv.x*w.y + dv.y*w.x);
        float2 t0 = make_float2(a.x + bb.x, a.y + bb.y);
        if (cur == 0) {
          S[line*K + o0] = t0; S[line*K + o1] = t1;
        } else {
          int d0i = axis ? (o0*P + b0 + line) : ((b0+line)*P + o0);
          int d1i = axis ? (o1*P + b0 + line) : ((b0+line)*P + o1);
          T[d0i] = t0; T[d1i] = t1;
        }
      }
      __syncthreads();
      cur ^= 1; l >>= 1; m <<= 1;
    }
    if (cur == 1) {                    // odd #stages: copy S back to T
      for (int t = tid; t < half*K; t += bs) {
        int line = t / K, e = t - (t/K)*K;
        int ti = axis ? (e*P + b0 + line) : ((b0+line)*P + e);
        T[ti] = S[line*K + e];
      }
      __syncthreads();
    }
  }
}

__global__ void k_trans(const float2* __restrict__ yl, int ylS,
                        const float* __restrict__ wig, int Lsyn,
                        float2* __restrict__ outX, float* __restrict__ outR,
                        int K, int fwd) {
  extern __shared__ float2 smc[];
  const int P = K + 1;
  float2* TW = smc;
  float2* T  = smc + K/2;
  float2* S  = T + K*P;
  const int tid = threadIdx.x, bs = blockDim.x;
  const int ci = blockIdx.x / K, k = blockIdx.x - ci*K;
  const int KK = K*K, Kh = K/2;
  const float c0 = 6.28318530717958647692f / K;
  for (int t = tid; t < Kh; t += bs) {
    float s, c; sincosf(c0 * (float)t, &s, &c);
    TW[t] = make_float2(c, -s);
  }
  // 1. build g tile (standard freq order)
  for (int idx = tid; idx < KK; idx += bs) {
    int fm = idx / K, fn = idx - (idx/K)*K;
    int m = (fm ^ Kh) - Kh, n = (fn ^ Kh) - Kh;
    int am = m < 0 ? -m : m, an = n < 0 ? -n : n;
    int lmin = am > an ? am : an;
    float2 acc = make_float2(0.f, 0.f);
    for (int l = lmin; l < Lsyn; ++l) {
      int d = 2*l+1;
      int r = (m+l)*d + (n+l);
      float wv = wig[(size_t)K*offl_(l) + (size_t)k*d*d + r];
      float2 yv = yl[(size_t)ci*ylS + offl_(l) + r];
      acc.x += wv*yv.x; acc.y += wv*yv.y;
    }
    T[fm*P + fn] = acc;
  }
  __syncthreads();
  // 2. inverse FFT2
  fft_axis(T, P, S, TW, K, 0, -1.f, tid, bs);
  fft_axis(T, P, S, TW, K, 1, -1.f, tid, bs);
  // 3. ReLU
  for (int idx = tid; idx < KK; idx += bs) {
    int fm = idx / K, fn = idx - (idx/K)*K;
    T[fm*P + fn] = make_float2(fmaxf(T[fm*P + fn].x, 0.f), 0.f);
  }
  __syncthreads();
  if (fwd) {
    fft_axis(T, P, S, TW, K, 0, 1.f, tid, bs);
    fft_axis(T, P, S, TW, K, 1, 1.f, tid, bs);
    float2* o = outX + ((size_t)ci*K + k)*KK;
    for (int idx = tid; idx < KK; idx += bs)
      o[idx] = T[(idx/K)*P + (idx - (idx/K)*K)];
  } else {
    float* o = outR + ((size_t)ci*K + k)*KK;
    for (int idx = tid; idx < KK; idx += bs)
      o[idx] = T[(idx/K)*P + (idx - (idx/K)*K)].x;
  }
}

// ---------------- Wigner analysis (X in STANDARD freq order) ----------------
__global__ void k_analysis(const float2* __restrict__ X, const float* __restrict__ wig,
                           const float* __restrict__ qw, float2* __restrict__ xh,
                           int BC, int K, int Sstride) {
  int l = blockIdx.y, d = 2*l+1, dd = d*d;
  long total = (long)BC*dd;
  long idx = (long)blockIdx.x*blockDim.x + threadIdx.x;
  if (idx >= total) return;
  int bc = (int)(idx / dd), r = (int)(idx % dd);
  int mi = r/d, ni = r - mi*d, m = mi-l, n = ni-l;
  const float* wl = wig + (long)K*offl_(l);
  int fm = (m + K) & (K-1), fn = (n + K) & (K-1);
  const float2* Xp = X + (long)bc*K*K*K + (long)fm*K + fn;
  float2 acc = make_float2(0.f, 0.f);
  for (int k = 0; k < K; ++k) {
    float w = qw[k] * wl[(long)k*dd + r];
    float2 xv = Xp[(long)k*K*K];
    acc.x += w*xv.x; acc.y += w*xv.y;
  }
  xh[(long)bc*Sstride + offl_(l) + r] = acc;
}

// s2 variant: XS2 is CENTERED (from k_dft1). stride 1024, offset l^2.
__global__ void k_analysis_s2(const float2* __restrict__ X, const float* __restrict__ wig,
                              const float* __restrict__ qw, float2* __restrict__ xh,
                              int BC, int K) {
  int l = blockIdx.y, d = 2*l+1, dd = d*d;
  long total = (long)BC*d;
  long idx = (long)blockIdx.x*blockDim.x + threadIdx.x;
  if (idx >= total) return;
  int bc = (int)(idx / d), mi = (int)(idx % d), m = mi - l;
  const float* wl = wig + (long)K*offl_(l);
  float2 acc = make_float2(0.f, 0.f);
  for (int k = 0; k < K; ++k) {
    float w = qw[k] * wl[(long)k*dd + mi*d + l];
    float2 xv = X[((long)bc*K + k)*K + (K/2+m)];
    acc.x += w*xv.x; acc.y += w*xv.y;
  }
  xh[(long)bc*1024 + l*l + mi] = acc;
}

// ---------------- 6x6 phase table of the SO(3) conv weights ----------------
__global__ void k_wf(const float* __restrict__ w, float2* __restrict__ wf, int CF) {
  long idx = (long)blockIdx.x*blockDim.x + threadIdx.x;
  if (idx >= (long)CF*36) return;
  int cf = (int)(idx / 36), r = (int)(idx % 36);
  int mm = r / 6, nn = r - (r/6)*6;
  const float* wp = w + (long)cf*36;
  float re = 0.f, im = 0.f;
  for (int a = 0; a < 6; ++a) {
    int pa = (mm*a) % 6;
    for (int g = 0; g < 6; ++g) {
      int p = (pa + nn*g) % 6;
      float wv = wp[a*6 + g];
      re += wv*COS6[p]; im += wv*SIN6[p];
    }
  }
  wf[idx] = make_float2(re, im);
}

// s2: kh[cf, l^2+mi] = d^l_{m,0}(b0) * sum_j w[cf,j] e^{-i m alpha_j}
__global__ void k_kh_s2(const float* __restrict__ w, const float* __restrict__ d0,
                        float2* __restrict__ kh, int C, int F) {
  int l = blockIdx.y, d = 2*l+1;
  long total = (long)C*F*d;
  long idx = (long)blockIdx.x*blockDim.x + threadIdx.x;
  if (idx >= total) return;
  int cf = (int)(idx / d), mi = (int)(idx % d), m = mi - l;
  const float* wp = w + (long)cf*6;
  float re = 0.f, im = 0.f;
  for (int j = 0; j < 6; ++j) {
    int p = ((-m*j) % 6 + 6) % 6;
    re += wp[j]*COS6[p]; im += wp[j]*SIN6[p];
  }
  float dv = d0[offl_(l) + mi*d + l];
  kh[(long)cf*1024 + l*l + mi] = make_float2(re*dv, im*dv);
}

// s2 rank-1: yl[b,f,m,n] = sum_c xh[b,c,m]*kh[c,f,n]
__global__ void k_rank1(const float2* __restrict__ xh, const float2* __restrict__ kh,
                        float2* __restrict__ yl, int B, int C, int F, int Sout) {
  int l = blockIdx.y, d = 2*l+1, dd = d*d;
  long total = (long)B*F*dd;
  long idx = (long)blockIdx.x*blockDim.x + threadIdx.x;
  if (idx >= total) return;
  int bf = (int)(idx / dd), r = (int)(idx % dd);
  int b = bf / F, f = bf - b*F;
  int mi = r/d, ni = r - mi*d;
  float2 acc = make_float2(0.f, 0.f);
  for (int c = 0; c < C; ++c) {
    float2 xv = xh[((long)b*C + c)*1024 + l*l + mi];
    float2 kv = kh[((long)c*F + f)*1024 + l*l + ni];
    acc.x += xv.x*kv.x - xv.y*kv.y;
    acc.y += xv.x*kv.y + xv.y*kv.x;
  }
  yl[(long)bf*Sout + offl_(l) + r] = acc;
}

// ---------------- legacy per-degree complex GEMM (kept for L==2) ----------------
#define GTM 32
#define GTN 64
#define GTK 16
__global__ __launch_bounds__(256)
void k_gemm(const float2* __restrict__ xh, int xhS,
            const float* __restrict__ d0, const float2* __restrict__ wf,
            float2* __restrict__ yl, int ylS,
            int B, int C, int F, int accf) {
  const int l = blockIdx.y, d = 2*l+1, ol = offl_(l);
  const int M = B*d, N = F*d, KD = C*d;
  const int tn_cnt = (N + GTN - 1)/GTN;
  const int tm_cnt = (M + GTM - 1)/GTM;
  const int tile = blockIdx.x;
  if (tile >= tm_cnt*tn_cnt) return;
  const int tm = tile / tn_cnt, tn = tile - tm*tn_cnt;
  const int r0 = tm*GTM, q0 = tn*GTN;
  __shared__ float2 As[GTK][GTM];
  __shared__ float2 Bs[GTK][GTN];
  const int tid = threadIdx.x;
  const int tx = tid & 15, ty = tid >> 4;
  float2 acc[2][4];
  for (int i = 0; i < 2; ++i)
    for (int j = 0; j < 4; ++j) acc[i][j] = make_float2(0.f, 0.f);

  for (int kt = 0; kt < KD; kt += GTK) {
    for (int idx = tid; idx < GTM*GTK; idx += 256) {
      int kk = idx / GTM, rr = idx - (idx/GTM)*GTM;
      int r = r0 + rr, t = kt + kk;
      float2 v = make_float2(0.f, 0.f);
      if (r < M && t < KD) {
        int b = r / d, mi = r - b*d;
        int c = t / d, p = t - c*d;
        v = xh[((size_t)b*C + c)*xhS + ol + (size_t)mi*d + p];
      }
      As[kk][rr] = v;
    }
    for (int idx = tid; idx < GTN*GTK; idx += 256) {
      int kk = idx / GTN, qq = idx - (idx/GTN)*GTN;
      int q = q0 + qq, t = kt + kk;
      float2 v = make_float2(0.f, 0.f);
      if (q < N && t < KD) {
        int f = q / d, ni = q - f*d;
        int c = t / d, p = t - c*d;
        int mm = (p - l) % 6; if (mm < 0) mm += 6;
        int nn = (ni - l) % 6; if (nn < 0) nn += 6;
        float dv = d0[ol + (size_t)p*d + ni];
        float2 wv = wf[((size_t)c*F + f)*36 + mm*6 + nn];
        v = make_float2(wv.x*dv, wv.y*dv);
      }
      Bs[kk][qq] = v;
    }
    __syncthreads();
    for (int kk = 0; kk < GTK; ++kk) {
      float2 a0 = As[kk][ty],      a1 = As[kk][ty+16];
      float2 b0 = Bs[kk][tx],      b1 = Bs[kk][tx+16];
      float2 b2 = Bs[kk][tx+32],   b3 = Bs[kk][tx+48];
      acc[0][0].x += a0.x*b0.x - a0.y*b0.y; acc[0][0].y += a0.x*b0.y + a0.y*b0.x;
      acc[0][1].x += a0.x*b1.x - a0.y*b1.y; acc[0][1].y += a0.x*b1.y + a0.y*b1.x;
      acc[0][2].x += a0.x*b2.x - a0.y*b2.y; acc[0][2].y += a0.x*b2.y + a0.y*b2.x;
      acc[0][3].x += a0.x*b3.x - a0.y*b3.y; acc[0][3].y += a0.x*b3.y + a0.y*b3.x;
      acc[1][0].x += a1.x*b0.x - a1.y*b0.y; acc[1][0].y += a1.x*b0.y + a1.y*b0.x;
      acc[1][1].x += a1.x*b1.x - a1.y*b1.y; acc[1][1].y += a1.x*b1.y + a1.y*b1.x;
      acc[1][2].x += a1.x*b2.x - a1.y*b2.y; acc[1][2].y += a1.x*b2.y + a1.y*b2.x;
      acc[1][3].x += a1.x*b3.x - a1.y*b3.y; acc[1][3].y += a1.x*b3.y + a1.y*b3.x;
    }
    __syncthreads();
  }

  for (int i = 0; i < 2; ++i) {
    int r = r0 + ty + 16*i;
    if (r >= M) continue;
    int b = r / d, mi = r - b*d;
    for (int j = 0; j < 4; ++j) {
      int q = q0 + tx + 16*j;
      if (q >= N) continue;
      int f = q / d, ni = q - f*d;
      float2* o = yl + ((size_t)b*F + f)*ylS + ol + (size_t)mi*d + ni;
      if (accf) { float2 v = *o; v.x += acc[i][j].x; v.y += acc[i][j].y; *o = v; }
      else *o = acc[i][j];
    }
  }
}

// ---------------- rank-6 factorized conv (used for L>=4) ----------------
// y[b,f,mi,ni] = sum_{c,mm} wf[c,f,mm,nn(ni)] * xt[b,c,mm,mi,ni]
// xt[b,c,mm,mi,ni] = sum_{p = (l+mm)%6, p+=6 < d} xh[b,c,mi,p] * d0[p,ni]
// GEMM view: cols u = b*d^2 + mi*d + ni (contiguous -> coalesced I/O),
//            rows f, K = 6C (uniform across l -> load-balanced).
// xt tile built on the fly into LDS (j-loop <= ceil(d/6) = 11).
#define G2M 64
#define G2F 16
#define G2K 16
__global__ __launch_bounds__(256)
void k_gemm2(const float2* __restrict__ xh, int xhS,
             const float* __restrict__ d0, const float2* __restrict__ wf,
             float2* __restrict__ yl, int ylS,
             int B, int C, int F, int accf) {
  const int l = blockIdx.y, d = 2*l+1, dd = d*d, ol = offl_(l);
  const int U = B*dd;
  const int nf_t = F >> 4;
  const int ct_cnt = (U + G2M - 1)/G2M;
  const int tile = blockIdx.x;
  if (tile >= ct_cnt*nf_t) return;
  const int ct = tile / nf_t, ft = tile - ct*nf_t;
  const int u0 = ct*G2M, f0 = ft*G2F;
  const int KD = 6*C;                       // multiple of 16 for all C here

  __shared__ float2 As[G2K][G2F*6];         // wf tile: [kk][fi*6+nn]
  __shared__ float2 Bs[G2K][G2M];           // xt tile: [kk][uu]

  const int tid = threadIdx.x;
  const int col = tid & 63;                 // lane-fast output column
  const int fr  = tid >> 6;                 // 0..3 (one per wave)

  // decode my output column (loop-invariant over K)
  int u = u0 + col;
  bool cvalid = (u < U);
  int b = 0, mi = 0, ni = 0, nnc = 0;
  if (cvalid) {
    b = u / dd; int rem = u - b*dd;
    mi = rem / d; ni = rem - mi*d;
    nnc = (ni - l) % 6; if (nnc < 0) nnc += 6;
  }
  int aoff[4];
  #pragma unroll
  for (int m = 0; m < 4; ++m) aoff[m] = (fr + 4*m)*6 + nnc;

  // precompute Bs-staging decode (4 fixed elements per thread)
  int    s_kk[4], s_db[4];
  size_t s_xb[4];
  bool   s_val[4];
  #pragma unroll
  for (int i = 0; i < 4; ++i) {
    int e = tid + 256*i;
    int kk = e >> 6, uu = e & 63;
    s_kk[i] = kk;
    int uC = u0 + uu;
    s_val[i] = (uC < U);
    if (s_val[i]) {
      int bb = uC / dd; int rem = uC - bb*dd;
      int mi_ = rem / d, ni_ = rem - mi_*d;
      s_xb[i] = ((size_t)bb*C)*xhS + ol + (size_t)mi_*d;
      s_db[i] = ol + ni_;
    } else { s_xb[i] = 0; s_db[i] = 0; }
  }

  float2 acc[4];
  #pragma unroll
  for (int m = 0; m < 4; ++m) acc[m] = make_float2(0.f, 0.f);

  for (int kt = 0; kt < KD; kt += G2K) {
    // stage Bs: compute xt values on the fly
    #pragma unroll
    for (int i = 0; i < 4; ++i) {
      int k2 = kt + s_kk[i];
      int c = k2 / 6, mm = k2 - c*6;
      int p0 = (l + mm) % 6;
      float2 v = make_float2(0.f, 0.f);
      if (s_val[i]) {
        const float2* xp = xh + s_xb[i] + (size_t)c*xhS;
        const float*  dp = d0 + s_db[i];
        for (int p = p0; p < d; p += 6) {
          float dv = dp[(size_t)p*d];
          float2 xv = xp[p];
          v.x += xv.x*dv; v.y += xv.y*dv;
        }
      }
      Bs[s_kk[i]][(tid + 256*i) & 63] = v;
    }
    // stage As: wf tile
    #pragma unroll
    for (int i = 0; i < 6; ++i) {
      int e = tid + 256*i;
      int kk = e / 96, r = e - kk*96;
      int fi = r / 6, nnw = r - fi*6;
      int k2 = kt + kk;
      int c = k2 / 6, mm = k2 - c*6;
      As[kk][r] = wf[((size_t)c*F + (f0 + fi))*36 + mm*6 + nnw];
    }
    __syncthreads();
    #pragma unroll
    for (int kk = 0; kk < G2K; ++kk) {
      float2 bv = Bs[kk][col];
      #pragma unroll
      for (int m = 0; m < 4; ++m) {
        float2 av = As[kk][aoff[m]];
        acc[m].x += bv.x*av.x - bv.y*av.y;
        acc[m].y += bv.x*av.y + bv.y*av.x;
      }
    }
    __syncthreads();
  }

  if (cvalid) {
    #pragma unroll
    for (int m = 0; m < 4; ++m) {
      int f = f0 + fr + 4*m;
      float2* o = yl + ((size_t)b*F + f)*ylS + ol + (size_t)mi*d + ni;
      if (accf) { float2 t = *o; t.x += acc[m].x; t.y += acc[m].y; *o = t; }
      else *o = acc[m];
    }
  }
}

// integrate over SO(3) at b=2 + linear head
__global__ void k_final(const float* __restrict__ h, const float* __restrict__ qw,
                        const float* __restrict__ lw, const float* __restrict__ lb,
                        float* __restrict__ out) {
  int b = blockIdx.x, f = threadIdx.x;
  const float* hp = h + ((long)b*256 + f)*64;
  float s = 0.f;
  for (int k = 0; k < 4; ++k) {
    float q = qw[k];
    for (int ag = 0; ag < 16; ++ag) s += hp[k*16 + ag]*q;
  }
  s = s * 0.0625f * lw[f];
  __shared__ float red[256];
  red[f] = s; __syncthreads();
  for (int st = 128; st > 0; st >>= 1) {
    if (f < st) red[f] += red[f + st];
    __syncthreads();
  }
  if (f == 0) out[b] = red[0] + lb[0];
}

// ============================================================================
extern "C" void kernel_launch(void* const* d_in, const int* in_sizes, int n_in,
                              void* d_out, int out_size, void* d_ws, size_t ws_size,
                              hipStream_t stream) {
  (void)in_sizes; (void)n_in;
  const float* x   = (const float*)d_in[0];
  const float* ks2 = (const float*)d_in[1];
  const float* lw  = (const float*)d_in[14];
  const float* lb  = (const float*)d_in[15];
  float* out = (float*)d_out;

  const int bl[5] = {32, 16, 8, 4, 2};
  char* ws = (char*)d_ws;
  size_t off = 0;
  auto alloc = [&](size_t nbytes) -> char* {
    char* p = ws + off;
    off += (nbytes + 255) & ~(size_t)255;
    return p;
  };

  double* lf = (double*)alloc(64*sizeof(double));
  float* qwT[5]; float* wigT[5]; float* d0T[4];
  for (int i = 0; i < 5; ++i) qwT[i]  = (float*)alloc((size_t)2*bl[i]*4);
  for (int i = 0; i < 5; ++i) wigT[i] = (float*)alloc((size_t)2*bl[i]*Sof(bl[i])*4);
  for (int i = 0; i < 4; ++i) d0T[i]  = (float*)alloc((size_t)Sof(bl[i])*4);

  float2* WF  = (float2*)alloc((size_t)128*256*36*8);   // 6x6 phase tables (max CF)
  float2* XH  = (float2*)alloc((size_t)64*43680*8);
  float2* YL  = (float2*)alloc((size_t)64*43680*8);
  float2* XHA = (float2*)alloc((size_t)64*5456*8);
  float2* XS2 = (float2*)alloc((size_t)1024*64*8);
  float2* XHS = (float2*)alloc((size_t)16*1024*8);
  float2* KHS = (float2*)alloc((size_t)64*1024*8);
  float*  OUTS= (float*)alloc((size_t)1024*64*4);
  size_t remain = (ws_size > off) ? (ws_size - off) : 0;
  size_t GCAP = remain > (64u<<20) ? (64u<<20) : (remain & ~(size_t)255);
  if (GCAP < (3u<<20)) {
    hipMemsetAsync(d_out, 0, (size_t)out_size*sizeof(float), stream);
    return;
  }
  float2* G = (float2*)alloc(GCAP);

  // ---- tables ----
  k_lf<<<1, 64, 0, stream>>>(lf);
  for (int i = 0; i < 5; ++i) k_qw<<<1, 64, 0, stream>>>(bl[i], qwT[i]);
  for (int i = 0; i < 5; ++i) {
    int L = bl[i], K = 2*L, md = 2*L-1;
    k_wigner<<<dim3(cdiv((long)K*md*md, 256), L), 256, 0, stream>>>(L, K, 0.0, lf, wigT[i]);
  }
  const double b0s[4] = {PI_D/16, PI_D/8, PI_D/4, PI_D/2};
  for (int i = 0; i < 4; ++i) {
    int L = bl[i], md = 2*L-1;
    k_wigner<<<dim3(cdiv((long)md*md, 256), L), 256, 0, stream>>>(L, 1, b0s[i], lf, d0T[i]);
  }

  // fused transition: yl -> [buildg+ifft2+relu+fft2] -> X chunks -> analysis -> xh
  auto transition = [&](const float2* yl, int ylS, int Lsyn, const float* wsyn,
                        int K, const float* wana, const float* qana,
                        int Lana, int Sana, float2* xh_out, int nsig) {
    long perX = (long)K*K*K;
    int CH = (int)((long)(GCAP/8)/perX);
    if (CH > nsig) CH = nsig;
    if (CH < 1) CH = 1;
    size_t lds = sizeof(float2)*((size_t)K/2 + (size_t)K*(K+1) + (size_t)K*K/2);
    int dd = (2*Lana-1)*(2*Lana-1);
    for (int s0 = 0; s0 < nsig; s0 += CH) {
      int ch = (nsig - s0 < CH) ? (nsig - s0) : CH;
      k_trans<<<ch*K, 256, lds, stream>>>(yl + (size_t)s0*ylS, ylS, wsyn, Lsyn,
                                          G, nullptr, K, 1);
      k_analysis<<<dim3(cdiv((long)ch*dd, 256), Lana), 256, 0, stream>>>(
          G, wana, qana, xh_out + (size_t)s0*Sana, ch, K, Sana);
    }
  };

  // conv: Wf table + one launch over all l.
  // L>=4: rank-6 factorized kernel (6/d + 1/(2F) of the FLOPs); L==2: legacy.
  auto conv = [&](const float* w, const float* d0, const float2* xh, int xhS,
                  float2* yl, int ylS, int B, int C, int F, int L, int accf) {
    k_wf<<<cdiv((long)C*F*36, 256), 256, 0, stream>>>(w, WF, C*F);
    if (L >= 4) {
      int dmax = 2*(L-1)+1;
      int tiles = cdiv((long)B*dmax*dmax, G2M) * (F >> 4);
      k_gemm2<<<dim3(tiles, L), 256, 0, stream>>>(xh, xhS, d0, WF, yl, ylS, B, C, F, accf);
    } else {
      int dmax = 2*(L-1)+1;
      int tiles = cdiv((long)B*dmax, GTM) * cdiv((long)F*dmax, GTN);
      k_gemm<<<dim3(tiles, L), 256, 0, stream>>>(xh, xhS, d0, WF, yl, ylS, B, C, F, accf);
    }
  };

  // ---- s2 conv (b=32) -> transition -> XH for block 1 ----
  k_dft1<<<1024, 64, 0, stream>>>(x, XS2, 64);
  k_analysis_s2<<<dim3(cdiv(16L*63, 256), 32), 256, 0, stream>>>(XS2, wigT[0], qwT[0], XHS, 16, 64);
  k_kh_s2<<<dim3(cdiv(64L*63, 256), 32), 256, 0, stream>>>(ks2, d0T[0], KHS, 4, 16);
  k_rank1<<<dim3(cdiv(64L*3969, 256), 32), 256, 0, stream>>>(XHS, KHS, YL, 4, 4, 16, 43680);
  transition(YL, 43680, 32, wigT[0], 64, wigT[0], qwT[0], 32, 43680, XH, 64);

  // ---- residual blocks ----
  const float* wa_[4] = {(const float*)d_in[2], (const float*)d_in[5], (const float*)d_in[8],  (const float*)d_in[11]};
  const float* wb_[4] = {(const float*)d_in[3], (const float*)d_in[6], (const float*)d_in[9],  (const float*)d_in[12]};
  const float* wsn[4] = {(const float*)d_in[4], (const float*)d_in[7], (const float*)d_in[10], (const float*)d_in[13]};
  const int Cs[4] = {16, 32, 64, 128}, Fs[4] = {32, 64, 128, 256};

  for (int blk = 0; blk < 4; ++blk) {
    const int bw = bl[blk], C = Cs[blk], F = Fs[blk], B = 4;
    const int L = bw, Lh = bw/2, K = 2*bw, Kh = bw;
    const int Sa = Sof(L), Sh = Sof(Lh);

    conv(wa_[blk], d0T[blk], XH, Sa, YL, Sa, B, C, C, L, 0);
    transition(YL, Sa, L, wigT[blk], K, wigT[blk], qwT[blk], Lh, Sh, XHA, B*C);
    conv(wb_[blk], d0T[blk], XHA, Sh, YL, Sh, B, C, F, Lh, 0);
    conv(wsn[blk], d0T[blk], XH, Sa, YL, Sh, B, C, F, Lh, 1);

    if (blk < 3) {
      transition(YL, Sh, Lh, wigT[blk+1], Kh, wigT[blk+1], qwT[blk+1], Lh, Sh, XH, B*F);
    } else {
      size_t lds = sizeof(float2)*((size_t)Kh/2 + (size_t)Kh*(Kh+1) + (size_t)Kh*Kh/2);
      k_trans<<<B*F*Kh, 256, lds, stream>>>(YL, Sh, wigT[4], Lh, nullptr, OUTS, Kh, 0);
    }
  }

  // ---- integrate (b=2) + linear head ----
  k_final<<<4, 256, 0, stream>>>(OUTS, qwT[4], lw, lb, out);
}

// Round 2
// 3737.666 us; speedup vs baseline: 1.5637x; 1.2036x over previous
//
#include <hip/hip_runtime.h>
#include <math.h>

// ============================================================================
// S2CNN regression — round 5.
//  R4 profile: k_trans (K=64) now dominant: 4 x ~510us, VALUBusy 56%,
//  occupancy 32%, HBM 3%. Causes: (1) runtime int division in FFT butterfly
//  index math (j=b/m with runtime m -> ~20-inst emulation, x2-3 per
//  butterfly); (2) LDS 48.75KB/block (T + Stockham ping-pong S) caps
//  occupancy at 3 blocks/CU.
//  This round: in-place DIF(ifft, nat->bitrev) + DIT(fft, bitrev->nat) —
//  the elementwise ReLU between them makes the bit-reversal free. Drops the
//  S buffer (LDS -> 33.5KB, 4 blocks/CU) and all copy-back passes. All
//  butterfly indexing is shift/mask (kshift passed in). 512 threads at K=64
//  -> 32 waves/CU. Wigner build-g loop uses incremental index updates
//  (no per-iter offl_ with div-by-3).
// ============================================================================

#define PI_D 3.14159265358979323846

__host__ __device__ __forceinline__ int offl_(int l) { return l*(2*l-1)*(2*l+1)/3; }
static inline int Sof(int b) { return b*(4*b*b-1)/3; }           // sum_{l<b}(2l+1)^2
static inline unsigned cdiv(long a, long b) { return (unsigned)((a + b - 1) / b); }

__device__ __constant__ float COS6[6] = {1.f, .5f, -.5f, -1.f, -.5f, .5f};
__device__ __constant__ float SIN6[6] = {0.f, 0.8660254037844386f, 0.8660254037844386f,
                                         0.f, -0.8660254037844386f, -0.8660254037844386f};

// ---------------- table generation ----------------
__global__ void k_lf(double* lf) {
  int n = threadIdx.x;
  double s = 0.0;
  for (int j = 2; j <= n; ++j) s += log((double)j);
  lf[n] = s;
}

__global__ void k_qw(int b, float* out) {
  int k = threadIdx.x, K = 2*b;
  if (k >= K) return;
  double beta = PI_D*(2*k+1)/(4.0*b);
  double s = 0.0;
  for (int j = 0; j < b; ++j)
    s += sin(PI_D*(double)(2*k+1)*(double)(2*j+1)/(4.0*b)) / (double)(2*j+1);
  out[k] = (float)((2.0/b)*sin(beta)*s);
}

// d^l_{m,n}(beta), explicit Jacobi sum, fp64.
// Layout: out[K*offl(l) + k*(2l+1)^2 + (m+l)*(2l+1) + (n+l)]
__global__ void k_wigner(int L, int K, double beta0, const double* __restrict__ lf,
                         float* __restrict__ out) {
  int l = blockIdx.y;
  int d = 2*l+1, dd = d*d;
  long total = (long)K*dd;
  long idx = (long)blockIdx.x*blockDim.x + threadIdx.x;
  if (idx >= total) return;
  int k = (int)(idx / dd), r = (int)(idx % dd);
  int mi = r/d, ni = r - mi*d, m = mi-l, n = ni-l;
  double beta = (K == 1) ? beta0 : PI_D*(double)(2*k+1)/(2.0*K);
  double cb = cos(0.5*beta), sb = sin(0.5*beta);
  double lc = log(cb), ls = log(sb);
  double pref = 0.5*(lf[l+m]+lf[l-m]+lf[l+n]+lf[l-n]);
  int smin = (n-m > 0) ? (n-m) : 0;
  int smax = (l+n < l-m) ? (l+n) : (l-m);
  double sum = 0.0;
  for (int s = smin; s <= smax; ++s) {
    double t = pref - lf[l+n-s] - lf[s] - lf[m-n+s] - lf[l-m-s]
             + (double)(2*l+n-m-2*s)*lc + (double)(m-n+2*s)*ls;
    double e = exp(t);
    sum += ((m-n+s) & 1) ? -e : e;
  }
  out[(long)K*offl_(l) + idx] = (float)sum;
}

// ---------------- s2 front: 1-D forward DFT (centered output) ----------------
__global__ void k_dft1(const float* __restrict__ in, float2* __restrict__ out, int K) {
  __shared__ float row[64];
  int tid = threadIdx.x;
  long base = (long)blockIdx.x * K;
  row[tid] = in[base + tid];
  __syncthreads();
  int i = tid;
  float2 acc = make_float2(0.f, 0.f);
  float c0 = 6.28318530717958647692f / K;
  for (int j = 0; j < K; ++j) {
    int r = (j * ((K + K/2 - i) & (K-1))) & (K-1);
    float s, c; sincosf(c0 * (float)r, &s, &c);
    acc.x += row[j]*c; acc.y += row[j]*s;
  }
  out[base + i] = acc;
}

// ---------------- in-place FFT passes (shift/mask indexing) ----------------
// DIF: natural input -> bit-reversed output. Butterfly: (a+b, (a-b)*w).
// AXIS=0 transforms along the fast index (row, stride 1);
// AXIS=1 along the slow index (column, stride P).
template <int AXIS>
__device__ __forceinline__ void fft_dif(float2* T, int P, const float2* TW,
                                        int K, int kshift, float fsign,
                                        int tid, int bs) {
  const int nb = (K >> 1) * K;
  const int bmask = (K >> 1) - 1;
  for (int s = 0; s < kshift; ++s) {
    const int hsh = kshift - 1 - s;
    const int h = 1 << hsh;
    for (int t = tid; t < nb; t += bs) {
      int line = t >> (kshift - 1);
      int b = t & bmask;
      int seg = b >> hsh, j = b & (h - 1);
      int i0 = (seg << (hsh + 1)) + j, i1 = i0 + h;
      int a0 = AXIS ? (i0*P + line) : (line*P + i0);
      int a1 = AXIS ? (i1*P + line) : (line*P + i1);
      float2 a = T[a0], c = T[a1];
      float2 w = TW[j << s]; w.y *= fsign;
      float2 dv = make_float2(a.x - c.x, a.y - c.y);
      T[a0] = make_float2(a.x + c.x, a.y + c.y);
      T[a1] = make_float2(dv.x*w.x - dv.y*w.y, dv.x*w.y + dv.y*w.x);
    }
    __syncthreads();
  }
}

// DIT: bit-reversed input -> natural output. Butterfly: (a+b*w, a-b*w).
template <int AXIS>
__device__ __forceinline__ void fft_dit(float2* T, int P, const float2* TW,
                                        int K, int kshift, float fsign,
                                        int tid, int bs) {
  const int nb = (K >> 1) * K;
  const int bmask = (K >> 1) - 1;
  for (int s = 0; s < kshift; ++s) {
    const int m = 1 << s;
    for (int t = tid; t < nb; t += bs) {
      int line = t >> (kshift - 1);
      int b = t & bmask;
      int seg = b >> s, j = b & (m - 1);
      int i0 = (seg << (s + 1)) + j, i1 = i0 + m;
      int a0 = AXIS ? (i0*P + line) : (line*P + i0);
      int a1 = AXIS ? (i1*P + line) : (line*P + i1);
      float2 a = T[a0], c = T[a1];
      float2 w = TW[j << (kshift - 1 - s)]; w.y *= fsign;
      float2 cw = make_float2(c.x*w.x - c.y*w.y, c.x*w.y + c.y*w.x);
      T[a0] = make_float2(a.x + cw.x, a.y + cw.y);
      T[a1] = make_float2(a.x - cw.x, a.y - cw.y);
    }
    __syncthreads();
  }
}

// ---------------- fused transition kernel ----------------
__global__ void k_trans(const float2* __restrict__ yl, int ylS,
                        const float* __restrict__ wig, int Lsyn,
                        float2* __restrict__ outX, float* __restrict__ outR,
                        int K, int kshift, int fwd) {
  extern __shared__ float2 smc[];
  const int P = K + 1;
  float2* TW = smc;
  float2* T  = smc + K/2;
  const int tid = threadIdx.x, bs = blockDim.x;
  const int ci = blockIdx.x >> kshift, k = blockIdx.x & (K-1);
  const int KK = K*K, Kh = K/2;
  const float c0 = 6.28318530717958647692f / K;
  for (int t = tid; t < Kh; t += bs) {
    float s, c; sincosf(c0 * (float)t, &s, &c);
    TW[t] = make_float2(c, -s);
  }
  // 1. build g tile (standard freq order), incremental index updates
  const float2* yb = yl + (size_t)ci*ylS;
  for (int idx = tid; idx < KK; idx += bs) {
    int fm = idx >> kshift, fn = idx & (K-1);
    int m = (fm ^ Kh) - Kh, n = (fn ^ Kh) - Kh;
    int am = m < 0 ? -m : m, an = n < 0 ? -n : n;
    int lmin = am > an ? am : an;
    float2 acc = make_float2(0.f, 0.f);
    if (lmin < Lsyn) {
      int d  = 2*lmin + 1;
      int d2 = d*d;
      int q  = (m + lmin)*d + (n + lmin);
      int ol = offl_(lmin);
      long wi = (long)K*ol + (long)k*d2 + q;
      long yi = (long)ol + q;
      for (int l = lmin; l < Lsyn; ++l) {
        float wv = wig[wi];
        float2 yv = yb[yi];
        acc.x += wv*yv.x; acc.y += wv*yv.y;
        int dq  = 2*m + 4*l + 4;      // q(l+1)-q(l)
        int dd2 = 8*l + 8;            // d2(l+1)-d2(l)
        wi += (long)K*d2 + (long)k*dd2 + dq;
        yi += d2 + dq;
        d2 += dd2;
      }
    }
    T[fm*P + fn] = acc;
  }
  __syncthreads();
  // 2. inverse FFT2: DIF, natural -> bit-reversed (both axes)
  fft_dif<0>(T, P, TW, K, kshift, -1.f, tid, bs);
  fft_dif<1>(T, P, TW, K, kshift, -1.f, tid, bs);
  // 3. ReLU (elementwise; bit-reversed positions are fine)
  for (int idx = tid; idx < KK; idx += bs) {
    int a = (idx >> kshift)*P + (idx & (K-1));
    T[a] = make_float2(fmaxf(T[a].x, 0.f), 0.f);
  }
  __syncthreads();
  if (fwd) {
    // 4. forward FFT2: DIT, bit-reversed -> natural
    fft_dit<0>(T, P, TW, K, kshift, 1.f, tid, bs);
    fft_dit<1>(T, P, TW, K, kshift, 1.f, tid, bs);
    float2* o = outX + ((size_t)ci*K + k)*KK;
    for (int idx = tid; idx < KK; idx += bs)
      o[idx] = T[(idx >> kshift)*P + (idx & (K-1))];
  } else {
    float* o = outR + ((size_t)ci*K + k)*KK;
    for (int idx = tid; idx < KK; idx += bs)
      o[idx] = T[(idx >> kshift)*P + (idx & (K-1))].x;
  }
}

// ---------------- Wigner analysis (X in STANDARD freq order) ----------------
__global__ void k_analysis(const float2* __restrict__ X, const float* __restrict__ wig,
                           const float* __restrict__ qw, float2* __restrict__ xh,
                           int BC, int K, int Sstride) {
  int l = blockIdx.y, d = 2*l+1, dd = d*d;
  long total = (long)BC*dd;
  long idx = (long)blockIdx.x*blockDim.x + threadIdx.x;
  if (idx >= total) return;
  int bc = (int)(idx / dd), r = (int)(idx % dd);
  int mi = r/d, ni = r - mi*d, m = mi-l, n = ni-l;
  const float* wl = wig + (long)K*offl_(l);
  int fm = (m + K) & (K-1), fn = (n + K) & (K-1);
  const float2* Xp = X + (long)bc*K*K*K + (long)fm*K + fn;
  float2 acc = make_float2(0.f, 0.f);
  for (int k = 0; k < K; ++k) {
    float w = qw[k] * wl[(long)k*dd + r];
    float2 xv = Xp[(long)k*K*K];
    acc.x += w*xv.x; acc.y += w*xv.y;
  }
  xh[(long)bc*Sstride + offl_(l) + r] = acc;
}

// s2 variant: XS2 is CENTERED (from k_dft1). stride 1024, offset l^2.
__global__ void k_analysis_s2(const float2* __restrict__ X, const float* __restrict__ wig,
                              const float* __restrict__ qw, float2* __restrict__ xh,
                              int BC, int K) {
  int l = blockIdx.y, d = 2*l+1, dd = d*d;
  long total = (long)BC*d;
  long idx = (long)blockIdx.x*blockDim.x + threadIdx.x;
  if (idx >= total) return;
  int bc = (int)(idx / d), mi = (int)(idx % d), m = mi - l;
  const float* wl = wig + (long)K*offl_(l);
  float2 acc = make_float2(0.f, 0.f);
  for (int k = 0; k < K; ++k) {
    float w = qw[k] * wl[(long)k*dd + mi*d + l];
    float2 xv = X[((long)bc*K + k)*K + (K/2+m)];
    acc.x += w*xv.x; acc.y += w*xv.y;
  }
  xh[(long)bc*1024 + l*l + mi] = acc;
}

// ---------------- 6x6 phase table of the SO(3) conv weights ----------------
__global__ void k_wf(const float* __restrict__ w, float2* __restrict__ wf, int CF) {
  long idx = (long)blockIdx.x*blockDim.x + threadIdx.x;
  if (idx >= (long)CF*36) return;
  int cf = (int)(idx / 36), r = (int)(idx % 36);
  int mm = r / 6, nn = r - (r/6)*6;
  const float* wp = w + (long)cf*36;
  float re = 0.f, im = 0.f;
  for (int a = 0; a < 6; ++a) {
    int pa = (mm*a) % 6;
    for (int g = 0; g < 6; ++g) {
      int p = (pa + nn*g) % 6;
      float wv = wp[a*6 + g];
      re += wv*COS6[p]; im += wv*SIN6[p];
    }
  }
  wf[idx] = make_float2(re, im);
}

// s2: kh[cf, l^2+mi] = d^l_{m,0}(b0) * sum_j w[cf,j] e^{-i m alpha_j}
__global__ void k_kh_s2(const float* __restrict__ w, const float* __restrict__ d0,
                        float2* __restrict__ kh, int C, int F) {
  int l = blockIdx.y, d = 2*l+1;
  long total = (long)C*F*d;
  long idx = (long)blockIdx.x*blockDim.x + threadIdx.x;
  if (idx >= total) return;
  int cf = (int)(idx / d), mi = (int)(idx % d), m = mi - l;
  const float* wp = w + (long)cf*6;
  float re = 0.f, im = 0.f;
  for (int j = 0; j < 6; ++j) {
    int p = ((-m*j) % 6 + 6) % 6;
    re += wp[j]*COS6[p]; im += wp[j]*SIN6[p];
  }
  float dv = d0[offl_(l) + mi*d + l];
  kh[(long)cf*1024 + l*l + mi] = make_float2(re*dv, im*dv);
}

// s2 rank-1: yl[b,f,m,n] = sum_c xh[b,c,m]*kh[c,f,n]
__global__ void k_rank1(const float2* __restrict__ xh, const float2* __restrict__ kh,
                        float2* __restrict__ yl, int B, int C, int F, int Sout) {
  int l = blockIdx.y, d = 2*l+1, dd = d*d;
  long total = (long)B*F*dd;
  long idx = (long)blockIdx.x*blockDim.x + threadIdx.x;
  if (idx >= total) return;
  int bf = (int)(idx / dd), r = (int)(idx % dd);
  int b = bf / F, f = bf - b*F;
  int mi = r/d, ni = r - mi*d;
  float2 acc = make_float2(0.f, 0.f);
  for (int c = 0; c < C; ++c) {
    float2 xv = xh[((long)b*C + c)*1024 + l*l + mi];
    float2 kv = kh[((long)c*F + f)*1024 + l*l + ni];
    acc.x += xv.x*kv.x - xv.y*kv.y;
    acc.y += xv.x*kv.y + xv.y*kv.x;
  }
  yl[(long)bf*Sout + offl_(l) + r] = acc;
}

// ---------------- legacy per-degree complex GEMM (kept for L==2) ----------------
#define GTM 32
#define GTN 64
#define GTK 16
__global__ __launch_bounds__(256)
void k_gemm(const float2* __restrict__ xh, int xhS,
            const float* __restrict__ d0, const float2* __restrict__ wf,
            float2* __restrict__ yl, int ylS,
            int B, int C, int F, int accf) {
  const int l = blockIdx.y, d = 2*l+1, ol = offl_(l);
  const int M = B*d, N = F*d, KD = C*d;
  const int tn_cnt = (N + GTN - 1)/GTN;
  const int tm_cnt = (M + GTM - 1)/GTM;
  const int tile = blockIdx.x;
  if (tile >= tm_cnt*tn_cnt) return;
  const int tm = tile / tn_cnt, tn = tile - tm*tn_cnt;
  const int r0 = tm*GTM, q0 = tn*GTN;
  __shared__ float2 As[GTK][GTM];
  __shared__ float2 Bs[GTK][GTN];
  const int tid = threadIdx.x;
  const int tx = tid & 15, ty = tid >> 4;
  float2 acc[2][4];
  for (int i = 0; i < 2; ++i)
    for (int j = 0; j < 4; ++j) acc[i][j] = make_float2(0.f, 0.f);

  for (int kt = 0; kt < KD; kt += GTK) {
    for (int idx = tid; idx < GTM*GTK; idx += 256) {
      int kk = idx / GTM, rr = idx - (idx/GTM)*GTM;
      int r = r0 + rr, t = kt + kk;
      float2 v = make_float2(0.f, 0.f);
      if (r < M && t < KD) {
        int b = r / d, mi = r - b*d;
        int c = t / d, p = t - c*d;
        v = xh[((size_t)b*C + c)*xhS + ol + (size_t)mi*d + p];
      }
      As[kk][rr] = v;
    }
    for (int idx = tid; idx < GTN*GTK; idx += 256) {
      int kk = idx / GTN, qq = idx - (idx/GTN)*GTN;
      int q = q0 + qq, t = kt + kk;
      float2 v = make_float2(0.f, 0.f);
      if (q < N && t < KD) {
        int f = q / d, ni = q - f*d;
        int c = t / d, p = t - c*d;
        int mm = (p - l) % 6; if (mm < 0) mm += 6;
        int nn = (ni - l) % 6; if (nn < 0) nn += 6;
        float dv = d0[ol + (size_t)p*d + ni];
        float2 wv = wf[((size_t)c*F + f)*36 + mm*6 + nn];
        v = make_float2(wv.x*dv, wv.y*dv);
      }
      Bs[kk][qq] = v;
    }
    __syncthreads();
    for (int kk = 0; kk < GTK; ++kk) {
      float2 a0 = As[kk][ty],      a1 = As[kk][ty+16];
      float2 b0 = Bs[kk][tx],      b1 = Bs[kk][tx+16];
      float2 b2 = Bs[kk][tx+32],   b3 = Bs[kk][tx+48];
      acc[0][0].x += a0.x*b0.x - a0.y*b0.y; acc[0][0].y += a0.x*b0.y + a0.y*b0.x;
      acc[0][1].x += a0.x*b1.x - a0.y*b1.y; acc[0][1].y += a0.x*b1.y + a0.y*b1.x;
      acc[0][2].x += a0.x*b2.x - a0.y*b2.y; acc[0][2].y += a0.x*b2.y + a0.y*b2.x;
      acc[0][3].x += a0.x*b3.x - a0.y*b3.y; acc[0][3].y += a0.x*b3.y + a0.y*b3.x;
      acc[1][0].x += a1.x*b0.x - a1.y*b0.y; acc[1][0].y += a1.x*b0.y + a1.y*b0.x;
      acc[1][1].x += a1.x*b1.x - a1.y*b1.y; acc[1][1].y += a1.x*b1.y + a1.y*b1.x;
      acc[1][2].x += a1.x*b2.x - a1.y*b2.y; acc[1][2].y += a1.x*b2.y + a1.y*b2.x;
      acc[1][3].x += a1.x*b3.x - a1.y*b3.y; acc[1][3].y += a1.x*b3.y + a1.y*b3.x;
    }
    __syncthreads();
  }

  for (int i = 0; i < 2; ++i) {
    int r = r0 + ty + 16*i;
    if (r >= M) continue;
    int b = r / d, mi = r - b*d;
    for (int j = 0; j < 4; ++j) {
      int q = q0 + tx + 16*j;
      if (q >= N) continue;
      int f = q / d, ni = q - f*d;
      float2* o = yl + ((size_t)b*F + f)*ylS + ol + (size_t)mi*d + ni;
      if (accf) { float2 v = *o; v.x += acc[i][j].x; v.y += acc[i][j].y; *o = v; }
      else *o = acc[i][j];
    }
  }
}

// ---------------- rank-6 factorized conv (used for L>=4) ----------------
#define G2M 64
#define G2F 16
#define G2K 16
__global__ __launch_bounds__(256)
void k_gemm2(const float2* __restrict__ xh, int xhS,
             const float* __restrict__ d0, const float2* __restrict__ wf,
             float2* __restrict__ yl, int ylS,
             int B, int C, int F, int accf) {
  const int l = blockIdx.y, d = 2*l+1, dd = d*d, ol = offl_(l);
  const int U = B*dd;
  const int nf_t = F >> 4;
  const int ct_cnt = (U + G2M - 1)/G2M;
  const int tile = blockIdx.x;
  if (tile >= ct_cnt*nf_t) return;
  const int ct = tile / nf_t, ft = tile - ct*nf_t;
  const int u0 = ct*G2M, f0 = ft*G2F;
  const int KD = 6*C;                       // multiple of 16 for all C here

  __shared__ float2 As[G2K][G2F*6];         // wf tile: [kk][fi*6+nn]
  __shared__ float2 Bs[G2K][G2M];           // xt tile: [kk][uu]

  const int tid = threadIdx.x;
  const int col = tid & 63;                 // lane-fast output column
  const int fr  = tid >> 6;                 // 0..3 (one per wave)

  int u = u0 + col;
  bool cvalid = (u < U);
  int b = 0, mi = 0, ni = 0, nnc = 0;
  if (cvalid) {
    b = u / dd; int rem = u - b*dd;
    mi = rem / d; ni = rem - mi*d;
    nnc = (ni - l) % 6; if (nnc < 0) nnc += 6;
  }
  int aoff[4];
  #pragma unroll
  for (int m = 0; m < 4; ++m) aoff[m] = (fr + 4*m)*6 + nnc;

  int    s_kk[4], s_db[4];
  size_t s_xb[4];
  bool   s_val[4];
  #pragma unroll
  for (int i = 0; i < 4; ++i) {
    int e = tid + 256*i;
    int kk = e >> 6, uu = e & 63;
    s_kk[i] = kk;
    int uC = u0 + uu;
    s_val[i] = (uC < U);
    if (s_val[i]) {
      int bb = uC / dd; int rem = uC - bb*dd;
      int mi_ = rem / d, ni_ = rem - mi_*d;
      s_xb[i] = ((size_t)bb*C)*xhS + ol + (size_t)mi_*d;
      s_db[i] = ol + ni_;
    } else { s_xb[i] = 0; s_db[i] = 0; }
  }

  float2 acc[4];
  #pragma unroll
  for (int m = 0; m < 4; ++m) acc[m] = make_float2(0.f, 0.f);

  for (int kt = 0; kt < KD; kt += G2K) {
    #pragma unroll
    for (int i = 0; i < 4; ++i) {
      int k2 = kt + s_kk[i];
      int c = k2 / 6, mm = k2 - c*6;
      int p0 = (l + mm) % 6;
      float2 v = make_float2(0.f, 0.f);
      if (s_val[i]) {
        const float2* xp = xh + s_xb[i] + (size_t)c*xhS;
        const float*  dp = d0 + s_db[i];
        for (int p = p0; p < d; p += 6) {
          float dv = dp[(size_t)p*d];
          float2 xv = xp[p];
          v.x += xv.x*dv; v.y += xv.y*dv;
        }
      }
      Bs[s_kk[i]][(tid + 256*i) & 63] = v;
    }
    #pragma unroll
    for (int i = 0; i < 6; ++i) {
      int e = tid + 256*i;
      int kk = e / 96, r = e - kk*96;
      int fi = r / 6, nnw = r - fi*6;
      int k2 = kt + kk;
      int c = k2 / 6, mm = k2 - c*6;
      As[kk][r] = wf[((size_t)c*F + (f0 + fi))*36 + mm*6 + nnw];
    }
    __syncthreads();
    #pragma unroll
    for (int kk = 0; kk < G2K; ++kk) {
      float2 bv = Bs[kk][col];
      #pragma unroll
      for (int m = 0; m < 4; ++m) {
        float2 av = As[kk][aoff[m]];
        acc[m].x += bv.x*av.x - bv.y*av.y;
        acc[m].y += bv.x*av.y + bv.y*av.x;
      }
    }
    __syncthreads();
  }

  if (cvalid) {
    #pragma unroll
    for (int m = 0; m < 4; ++m) {
      int f = f0 + fr + 4*m;
      float2* o = yl + ((size_t)b*F + f)*ylS + ol + (size_t)mi*d + ni;
      if (accf) { float2 t = *o; t.x += acc[m].x; t.y += acc[m].y; *o = t; }
      else *o = acc[m];
    }
  }
}

// integrate over SO(3) at b=2 + linear head
__global__ void k_final(const float* __restrict__ h, const float* __restrict__ qw,
                        const float* __restrict__ lw, const float* __restrict__ lb,
                        float* __restrict__ out) {
  int b = blockIdx.x, f = threadIdx.x;
  const float* hp = h + ((long)b*256 + f)*64;
  float s = 0.f;
  for (int k = 0; k < 4; ++k) {
    float q = qw[k];
    for (int ag = 0; ag < 16; ++ag) s += hp[k*16 + ag]*q;
  }
  s = s * 0.0625f * lw[f];
  __shared__ float red[256];
  red[f] = s; __syncthreads();
  for (int st = 128; st > 0; st >>= 1) {
    if (f < st) red[f] += red[f + st];
    __syncthreads();
  }
  if (f == 0) out[b] = red[0] + lb[0];
}

// ============================================================================
extern "C" void kernel_launch(void* const* d_in, const int* in_sizes, int n_in,
                              void* d_out, int out_size, void* d_ws, size_t ws_size,
                              hipStream_t stream) {
  (void)in_sizes; (void)n_in;
  const float* x   = (const float*)d_in[0];
  const float* ks2 = (const float*)d_in[1];
  const float* lw  = (const float*)d_in[14];
  const float* lb  = (const float*)d_in[15];
  float* out = (float*)d_out;

  const int bl[5] = {32, 16, 8, 4, 2};
  char* ws = (char*)d_ws;
  size_t off = 0;
  auto alloc = [&](size_t nbytes) -> char* {
    char* p = ws + off;
    off += (nbytes + 255) & ~(size_t)255;
    return p;
  };

  double* lf = (double*)alloc(64*sizeof(double));
  float* qwT[5]; float* wigT[5]; float* d0T[4];
  for (int i = 0; i < 5; ++i) qwT[i]  = (float*)alloc((size_t)2*bl[i]*4);
  for (int i = 0; i < 5; ++i) wigT[i] = (float*)alloc((size_t)2*bl[i]*Sof(bl[i])*4);
  for (int i = 0; i < 4; ++i) d0T[i]  = (float*)alloc((size_t)Sof(bl[i])*4);

  float2* WF  = (float2*)alloc((size_t)128*256*36*8);   // 6x6 phase tables (max CF)
  float2* XH  = (float2*)alloc((size_t)64*43680*8);
  float2* YL  = (float2*)alloc((size_t)64*43680*8);
  float2* XHA = (float2*)alloc((size_t)64*5456*8);
  float2* XS2 = (float2*)alloc((size_t)1024*64*8);
  float2* XHS = (float2*)alloc((size_t)16*1024*8);
  float2* KHS = (float2*)alloc((size_t)64*1024*8);
  float*  OUTS= (float*)alloc((size_t)1024*64*4);
  size_t remain = (ws_size > off) ? (ws_size - off) : 0;
  size_t GCAP = remain > (64u<<20) ? (64u<<20) : (remain & ~(size_t)255);
  if (GCAP < (3u<<20)) {
    hipMemsetAsync(d_out, 0, (size_t)out_size*sizeof(float), stream);
    return;
  }
  float2* G = (float2*)alloc(GCAP);

  // ---- tables ----
  k_lf<<<1, 64, 0, stream>>>(lf);
  for (int i = 0; i < 5; ++i) k_qw<<<1, 64, 0, stream>>>(bl[i], qwT[i]);
  for (int i = 0; i < 5; ++i) {
    int L = bl[i], K = 2*L, md = 2*L-1;
    k_wigner<<<dim3(cdiv((long)K*md*md, 256), L), 256, 0, stream>>>(L, K, 0.0, lf, wigT[i]);
  }
  const double b0s[4] = {PI_D/16, PI_D/8, PI_D/4, PI_D/2};
  for (int i = 0; i < 4; ++i) {
    int L = bl[i], md = 2*L-1;
    k_wigner<<<dim3(cdiv((long)md*md, 256), L), 256, 0, stream>>>(L, 1, b0s[i], lf, d0T[i]);
  }

  auto log2i = [](int v) { int s = 0; while ((1 << s) < v) ++s; return s; };

  // fused transition: yl -> [buildg+ifft2+relu+fft2] -> X chunks -> analysis -> xh
  auto transition = [&](const float2* yl, int ylS, int Lsyn, const float* wsyn,
                        int K, const float* wana, const float* qana,
                        int Lana, int Sana, float2* xh_out, int nsig) {
    long perX = (long)K*K*K;
    int CH = (int)((long)(GCAP/8)/perX);
    if (CH > nsig) CH = nsig;
    if (CH < 1) CH = 1;
    int ksh = log2i(K);
    int bs = (K >= 64) ? 512 : 256;
    size_t lds = sizeof(float2)*((size_t)K/2 + (size_t)K*(K+1));
    int dd = (2*Lana-1)*(2*Lana-1);
    for (int s0 = 0; s0 < nsig; s0 += CH) {
      int ch = (nsig - s0 < CH) ? (nsig - s0) : CH;
      k_trans<<<ch*K, bs, lds, stream>>>(yl + (size_t)s0*ylS, ylS, wsyn, Lsyn,
                                         G, nullptr, K, ksh, 1);
      k_analysis<<<dim3(cdiv((long)ch*dd, 256), Lana), 256, 0, stream>>>(
          G, wana, qana, xh_out + (size_t)s0*Sana, ch, K, Sana);
    }
  };

  // conv: Wf table + one launch over all l.
  auto conv = [&](const float* w, const float* d0, const float2* xh, int xhS,
                  float2* yl, int ylS, int B, int C, int F, int L, int accf) {
    k_wf<<<cdiv((long)C*F*36, 256), 256, 0, stream>>>(w, WF, C*F);
    if (L >= 4) {
      int dmax = 2*(L-1)+1;
      int tiles = cdiv((long)B*dmax*dmax, G2M) * (F >> 4);
      k_gemm2<<<dim3(tiles, L), 256, 0, stream>>>(xh, xhS, d0, WF, yl, ylS, B, C, F, accf);
    } else {
      int dmax = 2*(L-1)+1;
      int tiles = cdiv((long)B*dmax, GTM) * cdiv((long)F*dmax, GTN);
      k_gemm<<<dim3(tiles, L), 256, 0, stream>>>(xh, xhS, d0, WF, yl, ylS, B, C, F, accf);
    }
  };

  // ---- s2 conv (b=32) -> transition -> XH for block 1 ----
  k_dft1<<<1024, 64, 0, stream>>>(x, XS2, 64);
  k_analysis_s2<<<dim3(cdiv(16L*63, 256), 32), 256, 0, stream>>>(XS2, wigT[0], qwT[0], XHS, 16, 64);
  k_kh_s2<<<dim3(cdiv(64L*63, 256), 32), 256, 0, stream>>>(ks2, d0T[0], KHS, 4, 16);
  k_rank1<<<dim3(cdiv(64L*3969, 256), 32), 256, 0, stream>>>(XHS, KHS, YL, 4, 4, 16, 43680);
  transition(YL, 43680, 32, wigT[0], 64, wigT[0], qwT[0], 32, 43680, XH, 64);

  // ---- residual blocks ----
  const float* wa_[4] = {(const float*)d_in[2], (const float*)d_in[5], (const float*)d_in[8],  (const float*)d_in[11]};
  const float* wb_[4] = {(const float*)d_in[3], (const float*)d_in[6], (const float*)d_in[9],  (const float*)d_in[12]};
  const float* wsn[4] = {(const float*)d_in[4], (const float*)d_in[7], (const float*)d_in[10], (const float*)d_in[13]};
  const int Cs[4] = {16, 32, 64, 128}, Fs[4] = {32, 64, 128, 256};

  for (int blk = 0; blk < 4; ++blk) {
    const int bw = bl[blk], C = Cs[blk], F = Fs[blk], B = 4;
    const int L = bw, Lh = bw/2, K = 2*bw, Kh = bw;
    const int Sa = Sof(L), Sh = Sof(Lh);

    conv(wa_[blk], d0T[blk], XH, Sa, YL, Sa, B, C, C, L, 0);
    transition(YL, Sa, L, wigT[blk], K, wigT[blk], qwT[blk], Lh, Sh, XHA, B*C);
    conv(wb_[blk], d0T[blk], XHA, Sh, YL, Sh, B, C, F, Lh, 0);
    conv(wsn[blk], d0T[blk], XH, Sa, YL, Sh, B, C, F, Lh, 1);

    if (blk < 3) {
      transition(YL, Sh, Lh, wigT[blk+1], Kh, wigT[blk+1], qwT[blk+1], Lh, Sh, XH, B*F);
    } else {
      int ksh = log2i(Kh);
      size_t lds = sizeof(float2)*((size_t)Kh/2 + (size_t)Kh*(Kh+1));
      k_trans<<<B*F*Kh, 256, lds, stream>>>(YL, Sh, wigT[4], Lh, nullptr, OUTS, Kh, ksh, 0);
    }
  }

  // ---- integrate (b=2) + linear head ----
  k_final<<<4, 256, 0, stream>>>(OUTS, qwT[4], lw, lb, out);
}

// Round 3
// 3682.052 us; speedup vs baseline: 1.5874x; 1.0151x over previous
//
#include <hip/hip_runtime.h>
#include <math.h>

// ============================================================================
// S2CNN regression — round 6.
//  R5 profile: k_trans K=64 at 377us x4, occupancy 84%, VALUBusy only 41%,
//  bank conflicts UP to 13.9M -> LDS-pipe bound. Intra-row power-of-2 strides
//  at mid FFT stages give up to 16-way conflicts (seg*16 = 0 mod 16-pairs);
//  P=K+1 padding only fixes cross-row rotation.
//  This round:
//   * Fused radix-4 passes (two radix-2 stages combined in registers —
//     mathematically identical, so the DIF/DIT bit-reversal pairing is
//     unchanged): halves LDS ops, twiddle loads, and syncthreads.
//   * Hierarchical pad phi(c)=c+(c>>4), pitch P=(K+K/16)|1: spreads strided
//     column sets over all 16 bank-pairs (worst stage 16-way -> ~4-way).
//   * G chunk cap 64MB -> 256MB (single-chunk K=64 transitions, better L2
//     reuse of the Wigner table in k_analysis).
// ============================================================================

#define PI_D 3.14159265358979323846

__host__ __device__ __forceinline__ int offl_(int l) { return l*(2*l-1)*(2*l+1)/3; }
static inline int Sof(int b) { return b*(4*b*b-1)/3; }           // sum_{l<b}(2l+1)^2
static inline unsigned cdiv(long a, long b) { return (unsigned)((a + b - 1) / b); }

__device__ __constant__ float COS6[6] = {1.f, .5f, -.5f, -1.f, -.5f, .5f};
__device__ __constant__ float SIN6[6] = {0.f, 0.8660254037844386f, 0.8660254037844386f,
                                         0.f, -0.8660254037844386f, -0.8660254037844386f};

// physical column swizzle: one pad element after every 16 columns
__device__ __forceinline__ int phc(int c) { return c + (c >> 4); }
__host__ __device__ __forceinline__ int pitchK(int K) { return (K + (K >> 4)) | 1; }

__device__ __forceinline__ float2 cmulf(float2 a, float2 b) {
  return make_float2(a.x*b.x - a.y*b.y, a.x*b.y + a.y*b.x);
}

// ---------------- table generation ----------------
__global__ void k_lf(double* lf) {
  int n = threadIdx.x;
  double s = 0.0;
  for (int j = 2; j <= n; ++j) s += log((double)j);
  lf[n] = s;
}

__global__ void k_qw(int b, float* out) {
  int k = threadIdx.x, K = 2*b;
  if (k >= K) return;
  double beta = PI_D*(2*k+1)/(4.0*b);
  double s = 0.0;
  for (int j = 0; j < b; ++j)
    s += sin(PI_D*(double)(2*k+1)*(double)(2*j+1)/(4.0*b)) / (double)(2*j+1);
  out[k] = (float)((2.0/b)*sin(beta)*s);
}

// d^l_{m,n}(beta), explicit Jacobi sum, fp64.
__global__ void k_wigner(int L, int K, double beta0, const double* __restrict__ lf,
                         float* __restrict__ out) {
  int l = blockIdx.y;
  int d = 2*l+1, dd = d*d;
  long total = (long)K*dd;
  long idx = (long)blockIdx.x*blockDim.x + threadIdx.x;
  if (idx >= total) return;
  int k = (int)(idx / dd), r = (int)(idx % dd);
  int mi = r/d, ni = r - mi*d, m = mi-l, n = ni-l;
  double beta = (K == 1) ? beta0 : PI_D*(double)(2*k+1)/(2.0*K);
  double cb = cos(0.5*beta), sb = sin(0.5*beta);
  double lc = log(cb), ls = log(sb);
  double pref = 0.5*(lf[l+m]+lf[l-m]+lf[l+n]+lf[l-n]);
  int smin = (n-m > 0) ? (n-m) : 0;
  int smax = (l+n < l-m) ? (l+n) : (l-m);
  double sum = 0.0;
  for (int s = smin; s <= smax; ++s) {
    double t = pref - lf[l+n-s] - lf[s] - lf[m-n+s] - lf[l-m-s]
             + (double)(2*l+n-m-2*s)*lc + (double)(m-n+2*s)*ls;
    double e = exp(t);
    sum += ((m-n+s) & 1) ? -e : e;
  }
  out[(long)K*offl_(l) + idx] = (float)sum;
}

// ---------------- s2 front: 1-D forward DFT (centered output) ----------------
__global__ void k_dft1(const float* __restrict__ in, float2* __restrict__ out, int K) {
  __shared__ float row[64];
  int tid = threadIdx.x;
  long base = (long)blockIdx.x * K;
  row[tid] = in[base + tid];
  __syncthreads();
  int i = tid;
  float2 acc = make_float2(0.f, 0.f);
  float c0 = 6.28318530717958647692f / K;
  for (int j = 0; j < K; ++j) {
    int r = (j * ((K + K/2 - i) & (K-1))) & (K-1);
    float s, c; sincosf(c0 * (float)r, &s, &c);
    acc.x += row[j]*c; acc.y += row[j]*s;
  }
  out[base + i] = acc;
}

// ---------------- in-place FFT passes (fused radix-4, swizzled layout) -------
// AXIS=0: transform along columns within a row (row index = line).
// AXIS=1: transform along rows within a column (column index = line).
template <int AXIS>
__device__ __forceinline__ int taddr(int line, int i, int P) {
  return AXIS ? (i*P + phc(line)) : (line*P + phc(i));
}

// shared radix-2 unit stage (twiddle-free, h=m=1): used as DIF-final / DIT-pre
template <int AXIS>
__device__ __forceinline__ void fft_r2unit(float2* T, int P, int K, int kshift,
                                           int tid, int bs) {
  const int nb = (K >> 1) * K;
  const int bmask = (K >> 1) - 1;
  for (int t = tid; t < nb; t += bs) {
    int line = t >> (kshift - 1);
    int b = t & bmask;
    int c0 = b << 1, c1 = c0 + 1;
    int a0 = taddr<AXIS>(line, c0, P);
    int a1 = taddr<AXIS>(line, c1, P);
    float2 x = T[a0], y = T[a1];
    T[a0] = make_float2(x.x + y.x, x.y + y.y);
    T[a1] = make_float2(x.x - y.x, x.y - y.y);
  }
  __syncthreads();
}

// DIF: natural input -> bit-reversed output (two radix-2 stages fused).
template <int AXIS>
__device__ __forceinline__ void fft_dif(float2* T, int P, const float2* TW,
                                        int K, int kshift, float fsign,
                                        int tid, int bs) {
  const int nq = (K >> 2) * K;
  const int qmask = (K >> 2) - 1;
  const int lsh = kshift - 2;
  int s = 0;
  for (; s + 1 < kshift; s += 2) {
    const int hBsh = kshift - 2 - s;
    const int hB = 1 << hBsh;
    for (int t = tid; t < nq; t += bs) {
      int line = t >> lsh;
      int b = t & qmask;
      int seg = b >> hBsh, j = b & (hB - 1);
      int i0 = (seg << (hBsh + 2)) + j;
      int a0 = taddr<AXIS>(line, i0,        P);
      int a1 = taddr<AXIS>(line, i0 + hB,   P);
      int a2 = taddr<AXIS>(line, i0 + 2*hB, P);
      int a3 = taddr<AXIS>(line, i0 + 3*hB, P);
      float2 x0 = T[a0], x1 = T[a1], x2 = T[a2], x3 = T[a3];
      float2 wA = TW[j << s];       wA.y *= fsign;
      float2 wB = TW[j << (s + 1)]; wB.y *= fsign;
      // stage s (half 2hB): pairs (x0,x2)@j, (x1,x3)@j+hB  [tw(j+hB)=tw(j)*(-i*fsign)]
      float2 A0 = make_float2(x0.x + x2.x, x0.y + x2.y);
      float2 D0 = make_float2(x0.x - x2.x, x0.y - x2.y);
      float2 A1 = make_float2(x1.x + x3.x, x1.y + x3.y);
      float2 D1 = make_float2(x1.x - x3.x, x1.y - x3.y);
      float2 A2 = cmulf(D0, wA);
      float2 A3p = cmulf(D1, wA);
      float2 A3 = make_float2(fsign*A3p.y, -fsign*A3p.x);
      // stage s+1 (half hB): pairs (A0,A1)@j, (A2,A3)@j
      T[a0] = make_float2(A0.x + A1.x, A0.y + A1.y);
      T[a1] = cmulf(make_float2(A0.x - A1.x, A0.y - A1.y), wB);
      T[a2] = make_float2(A2.x + A3.x, A2.y + A3.y);
      T[a3] = cmulf(make_float2(A2.x - A3.x, A2.y - A3.y), wB);
    }
    __syncthreads();
  }
  if (s < kshift) fft_r2unit<AXIS>(T, P, K, kshift, tid, bs);  // s = kshift-1, w=1
}

// DIT: bit-reversed input -> natural output (two radix-2 stages fused).
template <int AXIS>
__device__ __forceinline__ void fft_dit(float2* T, int P, const float2* TW,
                                        int K, int kshift, float fsign,
                                        int tid, int bs) {
  const int nq = (K >> 2) * K;
  const int qmask = (K >> 2) - 1;
  const int lsh = kshift - 2;
  int s = 0;
  if (kshift & 1) {  // stage 0, m=1, w=1
    fft_r2unit<AXIS>(T, P, K, kshift, tid, bs);
    s = 1;
  }
  for (; s + 1 < kshift; s += 2) {
    const int m = 1 << s;
    for (int t = tid; t < nq; t += bs) {
      int line = t >> lsh;
      int b = t & qmask;
      int seg = b >> s, j = b & (m - 1);
      int i0 = (seg << (s + 2)) + j;
      int a0 = taddr<AXIS>(line, i0,       P);
      int a1 = taddr<AXIS>(line, i0 + m,   P);
      int a2 = taddr<AXIS>(line, i0 + 2*m, P);
      int a3 = taddr<AXIS>(line, i0 + 3*m, P);
      float2 x0 = T[a0], x1 = T[a1], x2 = T[a2], x3 = T[a3];
      float2 w1 = TW[j << (kshift - 1 - s)]; w1.y *= fsign;
      float2 w2 = TW[j << (kshift - 2 - s)]; w2.y *= fsign;
      // stage s: (x0,x1)@w1, (x2,x3)@w1
      float2 t1 = cmulf(x1, w1);
      float2 t3 = cmulf(x3, w1);
      float2 b0 = make_float2(x0.x + t1.x, x0.y + t1.y);
      float2 b1 = make_float2(x0.x - t1.x, x0.y - t1.y);
      float2 b2 = make_float2(x2.x + t3.x, x2.y + t3.y);
      float2 b3 = make_float2(x2.x - t3.x, x2.y - t3.y);
      // stage s+1: (b0,b2)@w2, (b1,b3)@w2*(-i*fsign)
      float2 u2 = cmulf(b2, w2);
      float2 u3p = cmulf(b3, w2);
      float2 u3 = make_float2(fsign*u3p.y, -fsign*u3p.x);
      T[a0] = make_float2(b0.x + u2.x, b0.y + u2.y);
      T[a2] = make_float2(b0.x - u2.x, b0.y - u2.y);
      T[a1] = make_float2(b1.x + u3.x, b1.y + u3.y);
      T[a3] = make_float2(b1.x - u3.x, b1.y - u3.y);
    }
    __syncthreads();
  }
}

// ---------------- fused transition kernel ----------------
__global__ void k_trans(const float2* __restrict__ yl, int ylS,
                        const float* __restrict__ wig, int Lsyn,
                        float2* __restrict__ outX, float* __restrict__ outR,
                        int K, int kshift, int fwd) {
  extern __shared__ float2 smc[];
  const int P = pitchK(K);
  float2* TW = smc;
  float2* T  = smc + K/2;
  const int tid = threadIdx.x, bs = blockDim.x;
  const int ci = blockIdx.x >> kshift, k = blockIdx.x & (K-1);
  const int KK = K*K, Kh = K/2;
  const float c0 = 6.28318530717958647692f / K;
  for (int t = tid; t < Kh; t += bs) {
    float s, c; sincosf(c0 * (float)t, &s, &c);
    TW[t] = make_float2(c, -s);
  }
  // 1. build g tile (standard freq order), incremental index updates
  const float2* yb = yl + (size_t)ci*ylS;
  for (int idx = tid; idx < KK; idx += bs) {
    int fm = idx >> kshift, fn = idx & (K-1);
    int m = (fm ^ Kh) - Kh, n = (fn ^ Kh) - Kh;
    int am = m < 0 ? -m : m, an = n < 0 ? -n : n;
    int lmin = am > an ? am : an;
    float2 acc = make_float2(0.f, 0.f);
    if (lmin < Lsyn) {
      int d  = 2*lmin + 1;
      int d2 = d*d;
      int q  = (m + lmin)*d + (n + lmin);
      int ol = offl_(lmin);
      long wi = (long)K*ol + (long)k*d2 + q;
      long yi = (long)ol + q;
      for (int l = lmin; l < Lsyn; ++l) {
        float wv = wig[wi];
        float2 yv = yb[yi];
        acc.x += wv*yv.x; acc.y += wv*yv.y;
        int dq  = 2*m + 4*l + 4;      // q(l+1)-q(l)
        int dd2 = 8*l + 8;            // d2(l+1)-d2(l)
        wi += (long)K*d2 + (long)k*dd2 + dq;
        yi += d2 + dq;
        d2 += dd2;
      }
    }
    T[fm*P + phc(fn)] = acc;
  }
  __syncthreads();
  // 2. inverse FFT2: DIF, natural -> bit-reversed (both axes)
  fft_dif<0>(T, P, TW, K, kshift, -1.f, tid, bs);
  fft_dif<1>(T, P, TW, K, kshift, -1.f, tid, bs);
  // 3. ReLU (elementwise; bit-reversed positions are fine)
  for (int idx = tid; idx < KK; idx += bs) {
    int a = (idx >> kshift)*P + phc(idx & (K-1));
    T[a] = make_float2(fmaxf(T[a].x, 0.f), 0.f);
  }
  __syncthreads();
  if (fwd) {
    // 4. forward FFT2: DIT, bit-reversed -> natural
    fft_dit<0>(T, P, TW, K, kshift, 1.f, tid, bs);
    fft_dit<1>(T, P, TW, K, kshift, 1.f, tid, bs);
    float2* o = outX + ((size_t)ci*K + k)*KK;
    for (int idx = tid; idx < KK; idx += bs)
      o[idx] = T[(idx >> kshift)*P + phc(idx & (K-1))];
  } else {
    float* o = outR + ((size_t)ci*K + k)*KK;
    for (int idx = tid; idx < KK; idx += bs)
      o[idx] = T[(idx >> kshift)*P + phc(idx & (K-1))].x;
  }
}

// ---------------- Wigner analysis (X in STANDARD freq order) ----------------
__global__ void k_analysis(const float2* __restrict__ X, const float* __restrict__ wig,
                           const float* __restrict__ qw, float2* __restrict__ xh,
                           int BC, int K, int Sstride) {
  int l = blockIdx.y, d = 2*l+1, dd = d*d;
  long total = (long)BC*dd;
  long idx = (long)blockIdx.x*blockDim.x + threadIdx.x;
  if (idx >= total) return;
  int bc = (int)(idx / dd), r = (int)(idx % dd);
  int mi = r/d, ni = r - mi*d, m = mi-l, n = ni-l;
  const float* wl = wig + (long)K*offl_(l);
  int fm = (m + K) & (K-1), fn = (n + K) & (K-1);
  const float2* Xp = X + (long)bc*K*K*K + (long)fm*K + fn;
  float2 acc = make_float2(0.f, 0.f);
  for (int k = 0; k < K; ++k) {
    float w = qw[k] * wl[(long)k*dd + r];
    float2 xv = Xp[(long)k*K*K];
    acc.x += w*xv.x; acc.y += w*xv.y;
  }
  xh[(long)bc*Sstride + offl_(l) + r] = acc;
}

// s2 variant: XS2 is CENTERED (from k_dft1). stride 1024, offset l^2.
__global__ void k_analysis_s2(const float2* __restrict__ X, const float* __restrict__ wig,
                              const float* __restrict__ qw, float2* __restrict__ xh,
                              int BC, int K) {
  int l = blockIdx.y, d = 2*l+1, dd = d*d;
  long total = (long)BC*d;
  long idx = (long)blockIdx.x*blockDim.x + threadIdx.x;
  if (idx >= total) return;
  int bc = (int)(idx / d), mi = (int)(idx % d), m = mi - l;
  const float* wl = wig + (long)K*offl_(l);
  float2 acc = make_float2(0.f, 0.f);
  for (int k = 0; k < K; ++k) {
    float w = qw[k] * wl[(long)k*dd + mi*d + l];
    float2 xv = X[((long)bc*K + k)*K + (K/2+m)];
    acc.x += w*xv.x; acc.y += w*xv.y;
  }
  xh[(long)bc*1024 + l*l + mi] = acc;
}

// ---------------- 6x6 phase table of the SO(3) conv weights ----------------
__global__ void k_wf(const float* __restrict__ w, float2* __restrict__ wf, int CF) {
  long idx = (long)blockIdx.x*blockDim.x + threadIdx.x;
  if (idx >= (long)CF*36) return;
  int cf = (int)(idx / 36), r = (int)(idx % 36);
  int mm = r / 6, nn = r - (r/6)*6;
  const float* wp = w + (long)cf*36;
  float re = 0.f, im = 0.f;
  for (int a = 0; a < 6; ++a) {
    int pa = (mm*a) % 6;
    for (int g = 0; g < 6; ++g) {
      int p = (pa + nn*g) % 6;
      float wv = wp[a*6 + g];
      re += wv*COS6[p]; im += wv*SIN6[p];
    }
  }
  wf[idx] = make_float2(re, im);
}

// s2: kh[cf, l^2+mi] = d^l_{m,0}(b0) * sum_j w[cf,j] e^{-i m alpha_j}
__global__ void k_kh_s2(const float* __restrict__ w, const float* __restrict__ d0,
                        float2* __restrict__ kh, int C, int F) {
  int l = blockIdx.y, d = 2*l+1;
  long total = (long)C*F*d;
  long idx = (long)blockIdx.x*blockDim.x + threadIdx.x;
  if (idx >= total) return;
  int cf = (int)(idx / d), mi = (int)(idx % d), m = mi - l;
  const float* wp = w + (long)cf*6;
  float re = 0.f, im = 0.f;
  for (int j = 0; j < 6; ++j) {
    int p = ((-m*j) % 6 + 6) % 6;
    re += wp[j]*COS6[p]; im += wp[j]*SIN6[p];
  }
  float dv = d0[offl_(l) + mi*d + l];
  kh[(long)cf*1024 + l*l + mi] = make_float2(re*dv, im*dv);
}

// s2 rank-1: yl[b,f,m,n] = sum_c xh[b,c,m]*kh[c,f,n]
__global__ void k_rank1(const float2* __restrict__ xh, const float2* __restrict__ kh,
                        float2* __restrict__ yl, int B, int C, int F, int Sout) {
  int l = blockIdx.y, d = 2*l+1, dd = d*d;
  long total = (long)B*F*dd;
  long idx = (long)blockIdx.x*blockDim.x + threadIdx.x;
  if (idx >= total) return;
  int bf = (int)(idx / dd), r = (int)(idx % dd);
  int b = bf / F, f = bf - b*F;
  int mi = r/d, ni = r - mi*d;
  float2 acc = make_float2(0.f, 0.f);
  for (int c = 0; c < C; ++c) {
    float2 xv = xh[((long)b*C + c)*1024 + l*l + mi];
    float2 kv = kh[((long)c*F + f)*1024 + l*l + ni];
    acc.x += xv.x*kv.x - xv.y*kv.y;
    acc.y += xv.x*kv.y + xv.y*kv.x;
  }
  yl[(long)bf*Sout + offl_(l) + r] = acc;
}

// ---------------- legacy per-degree complex GEMM (kept for L==2) ----------------
#define GTM 32
#define GTN 64
#define GTK 16
__global__ __launch_bounds__(256)
void k_gemm(const float2* __restrict__ xh, int xhS,
            const float* __restrict__ d0, const float2* __restrict__ wf,
            float2* __restrict__ yl, int ylS,
            int B, int C, int F, int accf) {
  const int l = blockIdx.y, d = 2*l+1, ol = offl_(l);
  const int M = B*d, N = F*d, KD = C*d;
  const int tn_cnt = (N + GTN - 1)/GTN;
  const int tm_cnt = (M + GTM - 1)/GTM;
  const int tile = blockIdx.x;
  if (tile >= tm_cnt*tn_cnt) return;
  const int tm = tile / tn_cnt, tn = tile - tm*tn_cnt;
  const int r0 = tm*GTM, q0 = tn*GTN;
  __shared__ float2 As[GTK][GTM];
  __shared__ float2 Bs[GTK][GTN];
  const int tid = threadIdx.x;
  const int tx = tid & 15, ty = tid >> 4;
  float2 acc[2][4];
  for (int i = 0; i < 2; ++i)
    for (int j = 0; j < 4; ++j) acc[i][j] = make_float2(0.f, 0.f);

  for (int kt = 0; kt < KD; kt += GTK) {
    for (int idx = tid; idx < GTM*GTK; idx += 256) {
      int kk = idx / GTM, rr = idx - (idx/GTM)*GTM;
      int r = r0 + rr, t = kt + kk;
      float2 v = make_float2(0.f, 0.f);
      if (r < M && t < KD) {
        int b = r / d, mi = r - b*d;
        int c = t / d, p = t - c*d;
        v = xh[((size_t)b*C + c)*xhS + ol + (size_t)mi*d + p];
      }
      As[kk][rr] = v;
    }
    for (int idx = tid; idx < GTN*GTK; idx += 256) {
      int kk = idx / GTN, qq = idx - (idx/GTN)*GTN;
      int q = q0 + qq, t = kt + kk;
      float2 v = make_float2(0.f, 0.f);
      if (q < N && t < KD) {
        int f = q / d, ni = q - f*d;
        int c = t / d, p = t - c*d;
        int mm = (p - l) % 6; if (mm < 0) mm += 6;
        int nn = (ni - l) % 6; if (nn < 0) nn += 6;
        float dv = d0[ol + (size_t)p*d + ni];
        float2 wv = wf[((size_t)c*F + f)*36 + mm*6 + nn];
        v = make_float2(wv.x*dv, wv.y*dv);
      }
      Bs[kk][qq] = v;
    }
    __syncthreads();
    for (int kk = 0; kk < GTK; ++kk) {
      float2 a0 = As[kk][ty],      a1 = As[kk][ty+16];
      float2 b0 = Bs[kk][tx],      b1 = Bs[kk][tx+16];
      float2 b2 = Bs[kk][tx+32],   b3 = Bs[kk][tx+48];
      acc[0][0].x += a0.x*b0.x - a0.y*b0.y; acc[0][0].y += a0.x*b0.y + a0.y*b0.x;
      acc[0][1].x += a0.x*b1.x - a0.y*b1.y; acc[0][1].y += a0.x*b1.y + a0.y*b1.x;
      acc[0][2].x += a0.x*b2.x - a0.y*b2.y; acc[0][2].y += a0.x*b2.y + a0.y*b2.x;
      acc[0][3].x += a0.x*b3.x - a0.y*b3.y; acc[0][3].y += a0.x*b3.y + a0.y*b3.x;
      acc[1][0].x += a1.x*b0.x - a1.y*b0.y; acc[1][0].y += a1.x*b0.y + a1.y*b0.x;
      acc[1][1].x += a1.x*b1.x - a1.y*b1.y; acc[1][1].y += a1.x*b1.y + a1.y*b1.x;
      acc[1][2].x += a1.x*b2.x - a1.y*b2.y; acc[1][2].y += a1.x*b2.y + a1.y*b2.x;
      acc[1][3].x += a1.x*b3.x - a1.y*b3.y; acc[1][3].y += a1.x*b3.y + a1.y*b3.x;
    }
    __syncthreads();
  }

  for (int i = 0; i < 2; ++i) {
    int r = r0 + ty + 16*i;
    if (r >= M) continue;
    int b = r / d, mi = r - b*d;
    for (int j = 0; j < 4; ++j) {
      int q = q0 + tx + 16*j;
      if (q >= N) continue;
      int f = q / d, ni = q - f*d;
      float2* o = yl + ((size_t)b*F + f)*ylS + ol + (size_t)mi*d + ni;
      if (accf) { float2 v = *o; v.x += acc[i][j].x; v.y += acc[i][j].y; *o = v; }
      else *o = acc[i][j];
    }
  }
}

// ---------------- rank-6 factorized conv (used for L>=4) ----------------
#define G2M 64
#define G2F 16
#define G2K 16
__global__ __launch_bounds__(256)
void k_gemm2(const float2* __restrict__ xh, int xhS,
             const float* __restrict__ d0, const float2* __restrict__ wf,
             float2* __restrict__ yl, int ylS,
             int B, int C, int F, int accf) {
  const int l = blockIdx.y, d = 2*l+1, dd = d*d, ol = offl_(l);
  const int U = B*dd;
  const int nf_t = F >> 4;
  const int ct_cnt = (U + G2M - 1)/G2M;
  const int tile = blockIdx.x;
  if (tile >= ct_cnt*nf_t) return;
  const int ct = tile / nf_t, ft = tile - ct*nf_t;
  const int u0 = ct*G2M, f0 = ft*G2F;
  const int KD = 6*C;                       // multiple of 16 for all C here

  __shared__ float2 As[G2K][G2F*6];         // wf tile: [kk][fi*6+nn]
  __shared__ float2 Bs[G2K][G2M];           // xt tile: [kk][uu]

  const int tid = threadIdx.x;
  const int col = tid & 63;                 // lane-fast output column
  const int fr  = tid >> 6;                 // 0..3 (one per wave)

  int u = u0 + col;
  bool cvalid = (u < U);
  int b = 0, mi = 0, ni = 0, nnc = 0;
  if (cvalid) {
    b = u / dd; int rem = u - b*dd;
    mi = rem / d; ni = rem - mi*d;
    nnc = (ni - l) % 6; if (nnc < 0) nnc += 6;
  }
  int aoff[4];
  #pragma unroll
  for (int m = 0; m < 4; ++m) aoff[m] = (fr + 4*m)*6 + nnc;

  int    s_kk[4], s_db[4];
  size_t s_xb[4];
  bool   s_val[4];
  #pragma unroll
  for (int i = 0; i < 4; ++i) {
    int e = tid + 256*i;
    int kk = e >> 6, uu = e & 63;
    s_kk[i] = kk;
    int uC = u0 + uu;
    s_val[i] = (uC < U);
    if (s_val[i]) {
      int bb = uC / dd; int rem = uC - bb*dd;
      int mi_ = rem / d, ni_ = rem - mi_*d;
      s_xb[i] = ((size_t)bb*C)*xhS + ol + (size_t)mi_*d;
      s_db[i] = ol + ni_;
    } else { s_xb[i] = 0; s_db[i] = 0; }
  }

  float2 acc[4];
  #pragma unroll
  for (int m = 0; m < 4; ++m) acc[m] = make_float2(0.f, 0.f);

  for (int kt = 0; kt < KD; kt += G2K) {
    #pragma unroll
    for (int i = 0; i < 4; ++i) {
      int k2 = kt + s_kk[i];
      int c = k2 / 6, mm = k2 - c*6;
      int p0 = (l + mm) % 6;
      float2 v = make_float2(0.f, 0.f);
      if (s_val[i]) {
        const float2* xp = xh + s_xb[i] + (size_t)c*xhS;
        const float*  dp = d0 + s_db[i];
        for (int p = p0; p < d; p += 6) {
          float dv = dp[(size_t)p*d];
          float2 xv = xp[p];
          v.x += xv.x*dv; v.y += xv.y*dv;
        }
      }
      Bs[s_kk[i]][(tid + 256*i) & 63] = v;
    }
    #pragma unroll
    for (int i = 0; i < 6; ++i) {
      int e = tid + 256*i;
      int kk = e / 96, r = e - kk*96;
      int fi = r / 6, nnw = r - fi*6;
      int k2 = kt + kk;
      int c = k2 / 6, mm = k2 - c*6;
      As[kk][r] = wf[((size_t)c*F + (f0 + fi))*36 + mm*6 + nnw];
    }
    __syncthreads();
    #pragma unroll
    for (int kk = 0; kk < G2K; ++kk) {
      float2 bv = Bs[kk][col];
      #pragma unroll
      for (int m = 0; m < 4; ++m) {
        float2 av = As[kk][aoff[m]];
        acc[m].x += bv.x*av.x - bv.y*av.y;
        acc[m].y += bv.x*av.y + bv.y*av.x;
      }
    }
    __syncthreads();
  }

  if (cvalid) {
    #pragma unroll
    for (int m = 0; m < 4; ++m) {
      int f = f0 + fr + 4*m;
      float2* o = yl + ((size_t)b*F + f)*ylS + ol + (size_t)mi*d + ni;
      if (accf) { float2 t = *o; t.x += acc[m].x; t.y += acc[m].y; *o = t; }
      else *o = acc[m];
    }
  }
}

// integrate over SO(3) at b=2 + linear head
__global__ void k_final(const float* __restrict__ h, const float* __restrict__ qw,
                        const float* __restrict__ lw, const float* __restrict__ lb,
                        float* __restrict__ out) {
  int b = blockIdx.x, f = threadIdx.x;
  const float* hp = h + ((long)b*256 + f)*64;
  float s = 0.f;
  for (int k = 0; k < 4; ++k) {
    float q = qw[k];
    for (int ag = 0; ag < 16; ++ag) s += hp[k*16 + ag]*q;
  }
  s = s * 0.0625f * lw[f];
  __shared__ float red[256];
  red[f] = s; __syncthreads();
  for (int st = 128; st > 0; st >>= 1) {
    if (f < st) red[f] += red[f + st];
    __syncthreads();
  }
  if (f == 0) out[b] = red[0] + lb[0];
}

// ============================================================================
extern "C" void kernel_launch(void* const* d_in, const int* in_sizes, int n_in,
                              void* d_out, int out_size, void* d_ws, size_t ws_size,
                              hipStream_t stream) {
  (void)in_sizes; (void)n_in;
  const float* x   = (const float*)d_in[0];
  const float* ks2 = (const float*)d_in[1];
  const float* lw  = (const float*)d_in[14];
  const float* lb  = (const float*)d_in[15];
  float* out = (float*)d_out;

  const int bl[5] = {32, 16, 8, 4, 2};
  char* ws = (char*)d_ws;
  size_t off = 0;
  auto alloc = [&](size_t nbytes) -> char* {
    char* p = ws + off;
    off += (nbytes + 255) & ~(size_t)255;
    return p;
  };

  double* lf = (double*)alloc(64*sizeof(double));
  float* qwT[5]; float* wigT[5]; float* d0T[4];
  for (int i = 0; i < 5; ++i) qwT[i]  = (float*)alloc((size_t)2*bl[i]*4);
  for (int i = 0; i < 5; ++i) wigT[i] = (float*)alloc((size_t)2*bl[i]*Sof(bl[i])*4);
  for (int i = 0; i < 4; ++i) d0T[i]  = (float*)alloc((size_t)Sof(bl[i])*4);

  float2* WF  = (float2*)alloc((size_t)128*256*36*8);   // 6x6 phase tables (max CF)
  float2* XH  = (float2*)alloc((size_t)64*43680*8);
  float2* YL  = (float2*)alloc((size_t)64*43680*8);
  float2* XHA = (float2*)alloc((size_t)64*5456*8);
  float2* XS2 = (float2*)alloc((size_t)1024*64*8);
  float2* XHS = (float2*)alloc((size_t)16*1024*8);
  float2* KHS = (float2*)alloc((size_t)64*1024*8);
  float*  OUTS= (float*)alloc((size_t)1024*64*4);
  size_t remain = (ws_size > off) ? (ws_size - off) : 0;
  size_t GCAP = remain > (256u<<20) ? (size_t)(256u<<20) : (remain & ~(size_t)255);
  if (GCAP < (3u<<20)) {
    hipMemsetAsync(d_out, 0, (size_t)out_size*sizeof(float), stream);
    return;
  }
  float2* G = (float2*)alloc(GCAP);

  // ---- tables ----
  k_lf<<<1, 64, 0, stream>>>(lf);
  for (int i = 0; i < 5; ++i) k_qw<<<1, 64, 0, stream>>>(bl[i], qwT[i]);
  for (int i = 0; i < 5; ++i) {
    int L = bl[i], K = 2*L, md = 2*L-1;
    k_wigner<<<dim3(cdiv((long)K*md*md, 256), L), 256, 0, stream>>>(L, K, 0.0, lf, wigT[i]);
  }
  const double b0s[4] = {PI_D/16, PI_D/8, PI_D/4, PI_D/2};
  for (int i = 0; i < 4; ++i) {
    int L = bl[i], md = 2*L-1;
    k_wigner<<<dim3(cdiv((long)md*md, 256), L), 256, 0, stream>>>(L, 1, b0s[i], lf, d0T[i]);
  }

  auto log2i = [](int v) { int s = 0; while ((1 << s) < v) ++s; return s; };

  // fused transition: yl -> [buildg+ifft2+relu+fft2] -> X chunks -> analysis -> xh
  auto transition = [&](const float2* yl, int ylS, int Lsyn, const float* wsyn,
                        int K, const float* wana, const float* qana,
                        int Lana, int Sana, float2* xh_out, int nsig) {
    long perX = (long)K*K*K;
    int CH = (int)((long)(GCAP/8)/perX);
    if (CH > nsig) CH = nsig;
    if (CH < 1) CH = 1;
    int ksh = log2i(K);
    int bs = (K >= 64) ? 512 : 256;
    int P = pitchK(K);
    size_t lds = sizeof(float2)*((size_t)K/2 + (size_t)K*P);
    int dd = (2*Lana-1)*(2*Lana-1);
    for (int s0 = 0; s0 < nsig; s0 += CH) {
      int ch = (nsig - s0 < CH) ? (nsig - s0) : CH;
      k_trans<<<ch*K, bs, lds, stream>>>(yl + (size_t)s0*ylS, ylS, wsyn, Lsyn,
                                         G, nullptr, K, ksh, 1);
      k_analysis<<<dim3(cdiv((long)ch*dd, 256), Lana), 256, 0, stream>>>(
          G, wana, qana, xh_out + (size_t)s0*Sana, ch, K, Sana);
    }
  };

  // conv: Wf table + one launch over all l.
  auto conv = [&](const float* w, const float* d0, const float2* xh, int xhS,
                  float2* yl, int ylS, int B, int C, int F, int L, int accf) {
    k_wf<<<cdiv((long)C*F*36, 256), 256, 0, stream>>>(w, WF, C*F);
    if (L >= 4) {
      int dmax = 2*(L-1)+1;
      int tiles = cdiv((long)B*dmax*dmax, G2M) * (F >> 4);
      k_gemm2<<<dim3(tiles, L), 256, 0, stream>>>(xh, xhS, d0, WF, yl, ylS, B, C, F, accf);
    } else {
      int dmax = 2*(L-1)+1;
      int tiles = cdiv((long)B*dmax, GTM) * cdiv((long)F*dmax, GTN);
      k_gemm<<<dim3(tiles, L), 256, 0, stream>>>(xh, xhS, d0, WF, yl, ylS, B, C, F, accf);
    }
  };

  // ---- s2 conv (b=32) -> transition -> XH for block 1 ----
  k_dft1<<<1024, 64, 0, stream>>>(x, XS2, 64);
  k_analysis_s2<<<dim3(cdiv(16L*63, 256), 32), 256, 0, stream>>>(XS2, wigT[0], qwT[0], XHS, 16, 64);
  k_kh_s2<<<dim3(cdiv(64L*63, 256), 32), 256, 0, stream>>>(ks2, d0T[0], KHS, 4, 16);
  k_rank1<<<dim3(cdiv(64L*3969, 256), 32), 256, 0, stream>>>(XHS, KHS, YL, 4, 4, 16, 43680);
  transition(YL, 43680, 32, wigT[0], 64, wigT[0], qwT[0], 32, 43680, XH, 64);

  // ---- residual blocks ----
  const float* wa_[4] = {(const float*)d_in[2], (const float*)d_in[5], (const float*)d_in[8],  (const float*)d_in[11]};
  const float* wb_[4] = {(const float*)d_in[3], (const float*)d_in[6], (const float*)d_in[9],  (const float*)d_in[12]};
  const float* wsn[4] = {(const float*)d_in[4], (const float*)d_in[7], (const float*)d_in[10], (const float*)d_in[13]};
  const int Cs[4] = {16, 32, 64, 128}, Fs[4] = {32, 64, 128, 256};

  for (int blk = 0; blk < 4; ++blk) {
    const int bw = bl[blk], C = Cs[blk], F = Fs[blk], B = 4;
    const int L = bw, Lh = bw/2, K = 2*bw, Kh = bw;
    const int Sa = Sof(L), Sh = Sof(Lh);

    conv(wa_[blk], d0T[blk], XH, Sa, YL, Sa, B, C, C, L, 0);
    transition(YL, Sa, L, wigT[blk], K, wigT[blk], qwT[blk], Lh, Sh, XHA, B*C);
    conv(wb_[blk], d0T[blk], XHA, Sh, YL, Sh, B, C, F, Lh, 0);
    conv(wsn[blk], d0T[blk], XH, Sa, YL, Sh, B, C, F, Lh, 1);

    if (blk < 3) {
      transition(YL, Sh, Lh, wigT[blk+1], Kh, wigT[blk+1], qwT[blk+1], Lh, Sh, XH, B*F);
    } else {
      int ksh = log2i(Kh);
      int P = pitchK(Kh);
      size_t lds = sizeof(float2)*((size_t)Kh/2 + (size_t)Kh*P);
      k_trans<<<B*F*Kh, 256, lds, stream>>>(YL, Sh, wigT[4], Lh, nullptr, OUTS, Kh, ksh, 0);
    }
  }

  // ---- integrate (b=2) + linear head ----
  k_final<<<4, 256, 0, stream>>>(OUTS, qwT[4], lw, lb, out);
}